// Round 10
// baseline (251.263 us; speedup 1.0000x reference)
//
#include <hip/hip_runtime.h>
#include <hip/hip_bf16.h>
#include <stdint.h>

typedef __attribute__((ext_vector_type(8))) short short8;
typedef __attribute__((ext_vector_type(4))) float f32x4;

#define T_DIM 256
#define NBATCH 64

__device__ __forceinline__ void gload_lds16(const void* g, void* l) {
    __builtin_amdgcn_global_load_lds(
        (const __attribute__((address_space(1))) void*)g,
        (__attribute__((address_space(3))) void*)l, 16, 0, 0);
}

// ---------------- prep: W [(K+1)][O] fp32 -> WT_hi/WT_lo [O][K] bf16 + bias[O] ----
__global__ void prep_w(const float* __restrict__ W, __hip_bfloat16* __restrict__ WTh,
                       __hip_bfloat16* __restrict__ WTl, float* __restrict__ bias,
                       int K, int O) {
    int idx = blockIdx.x * blockDim.x + threadIdx.x;
    int total = O * K;
    if (idx < total) {
        int o = idx / K, i = idx % K;
        float w = W[(size_t)i * O + o];
        __hip_bfloat16 h = __float2bfloat16(w);
        WTh[idx] = h;
        WTl[idx] = __float2bfloat16(w - __bfloat162float(h));
    }
    if (idx < O) bias[idx] = W[(size_t)K * O + idx];
}

// ---------------- prep: x [64][512][256] fp32 -> xh/xl [64][256][512] bf16 --------
__global__ void prep_x(const float* __restrict__ x, __hip_bfloat16* __restrict__ xh,
                       __hip_bfloat16* __restrict__ xl) {
    __shared__ float tile[32][33];
    int b = blockIdx.z;
    int i0 = blockIdx.x * 32;
    int t0 = blockIdx.y * 32;
    int tx = threadIdx.x;
    int ty = threadIdx.y;
    for (int dy = 0; dy < 32; dy += 8)
        tile[ty + dy][tx] = x[((size_t)b * 512 + i0 + ty + dy) * T_DIM + t0 + tx];
    __syncthreads();
    for (int dy = 0; dy < 32; dy += 8) {
        float w = tile[tx][ty + dy];
        size_t dst = ((size_t)b * T_DIM + t0 + ty + dy) * 512 + i0 + tx;
        __hip_bfloat16 h = __float2bfloat16(w);
        xh[dst] = h;
        xl[dst] = __float2bfloat16(w - __bfloat162float(h));
    }
}

// ======== shared epilogue: in-block LIF scan over t=0..255, carry in registers =====
// acc[i][j]: i = o-frag (128 o rows), j = t-frag within wave (wave wn owns t span
// [wn*64, wn*64+64)).  Chunk tc is dumped by wave wn==tc into fpool [64t][132o],
// then 128 threads (one per o) advance the membrane scan 64 steps.
#define LIF_EPILOGUE(POOL, ACC, O_TOTAL)                                             \
    {                                                                                \
        float sb = 1.f / (1.f + expf(-beta_p[0]));                                   \
        float thrv = thr_p[0];                                                       \
        float* fpool = (float*)(POOL);                                               \
        float mem = 0.f;                                                             \
        for (int tc = 0; tc < 4; ++tc) {                                             \
            __syncthreads();                                                         \
            if (wn == tc) {                                                          \
                _Pragma("unroll") for (int i = 0; i < 8; ++i) {                      \
                    int o = i * 16 + ((lane >> 4) * 4);                              \
                    f32x4 bv = *(const f32x4*)(bias + o0 + o);                       \
                    _Pragma("unroll") for (int j = 0; j < 4; ++j) {                  \
                        int tl = j * 16 + (lane & 15);                               \
                        *(f32x4*)(fpool + tl * 132 + o) = ACC[i][j] + bv;            \
                    }                                                                \
                }                                                                    \
            }                                                                        \
            __syncthreads();                                                         \
            if (tid < 128) {                                                         \
                _Pragma("unroll 4") for (int ttl = 0; ttl < 64; ++ttl) {             \
                    float mu = __fadd_rn(__fmul_rn(sb, mem), fpool[ttl * 132 + tid]);\
                    float spike = (mu >= thrv) ? 1.f : 0.f;                          \
                    mem = mu - spike * thrv;                                         \
                    Sout[((size_t)b * T_DIM + tc * 64 + ttl) * (O_TOTAL) + o0 + tid] \
                        = __float2bfloat16(spike);                                   \
                }                                                                    \
            }                                                                        \
        }                                                                            \
    }

// ---------------- layer-1: plane-fused GEMM (whole-t block) + fused LIF -----------
// S1[b][t][o] = LIF(Wh·xh + Wh·xl + Wl·xh + bias).  Tile 128(o) x 256(t), 4 waves
// (1M x 4N, per-wave 128x64), BK=64, acc[8][4].  LDS 80KB: Wh/Wl slot 16K + xh 32K
// + xl 32K -> 2 blocks/CU, grid 512 = 2/CU.  Phase1 (8 steps): 128 MFMA/step
// (Wh·xh + Wh·xl); phase2 (8 steps): 64 MFMA/step (Wl·xh).  Per-element accumulation
// order identical to round-9 -> bit-identical (absmax canary 2.058594).
__global__ __launch_bounds__(256) void gemm_lif_l1(
    const __hip_bfloat16* __restrict__ Wh, const __hip_bfloat16* __restrict__ Wl,
    const __hip_bfloat16* __restrict__ xh, const __hip_bfloat16* __restrict__ xl,
    const float* __restrict__ bias, __hip_bfloat16* __restrict__ Sout,
    const float* __restrict__ beta_p, const float* __restrict__ thr_p, int nOx) {
    const int K = 512;
    __shared__ __align__(16) char pool[81920];
    char* Ws  = pool;            // 16KB (Wh phase1 / Wl phase2)
    char* xhs = pool + 16384;    // 32KB (256 rows)
    char* xls = pool + 49152;    // 32KB

    const int fid = blockIdx.x;
    const int xcd = fid & 7;
    const int k_in = fid >> 3;
    const int b = xcd * 8 + k_in / nOx;
    const int o0 = (k_in % nOx) * 128;

    const int tid = threadIdx.x;
    const int lane = tid & 63;
    const int wn = tid >> 6;     // wave = t-split (1M x 4N)

    f32x4 acc[8][4] = {};

    const int srow = tid >> 3;          // 0..31
    const int skb  = (tid & 7) * 16;
    const int src_kb = skb ^ ((srow & 7) << 4);

    const __hip_bfloat16* xhB = xh + (size_t)b * T_DIM * K;
    const __hip_bfloat16* xlB = xl + (size_t)b * T_DIM * K;

    // ---- phase 1: Wh·xh + Wh·xl ----
    for (int k0 = 0; k0 < K; k0 += 64) {
#pragma unroll
        for (int r = 0; r < 4; ++r) {
            int row = srow + r * 32;
            gload_lds16((const char*)(Wh + (size_t)(o0 + row) * K + k0) + src_kb,
                        Ws + row * 128 + skb);
        }
#pragma unroll
        for (int r = 0; r < 8; ++r) {
            int row = srow + r * 32;   // 0..255
            gload_lds16((const char*)(xhB + (size_t)row * K + k0) + src_kb,
                        xhs + row * 128 + skb);
            gload_lds16((const char*)(xlB + (size_t)row * K + k0) + src_kb,
                        xls + row * 128 + skb);
        }
        __syncthreads();
#pragma unroll
        for (int kk = 0; kk < 2; ++kk) {
            short8 b0[4], b1[4];
#pragma unroll
            for (int j = 0; j < 4; ++j) {
                int row = wn * 64 + j * 16 + (lane & 15);
                int kb = ((((lane >> 4) * 8) + kk * 32) * 2) ^ ((row & 7) << 4);
                b0[j] = *(const short8*)(xhs + row * 128 + kb);
                b1[j] = *(const short8*)(xls + row * 128 + kb);
            }
#pragma unroll
            for (int i = 0; i < 8; ++i) {
                int row = i * 16 + (lane & 15);
                int kb = ((((lane >> 4) * 8) + kk * 32) * 2) ^ ((row & 7) << 4);
                short8 ah = *(const short8*)(Ws + row * 128 + kb);
#pragma unroll
                for (int j = 0; j < 4; ++j)
                    acc[i][j] = __builtin_amdgcn_mfma_f32_16x16x32_bf16(
                        ah, b0[j], acc[i][j], 0, 0, 0);
#pragma unroll
                for (int j = 0; j < 4; ++j)
                    acc[i][j] = __builtin_amdgcn_mfma_f32_16x16x32_bf16(
                        ah, b1[j], acc[i][j], 0, 0, 0);
            }
        }
        __syncthreads();
    }

    // ---- phase 2: += Wl·xh ----
    for (int k0 = 0; k0 < K; k0 += 64) {
#pragma unroll
        for (int r = 0; r < 4; ++r) {
            int row = srow + r * 32;
            gload_lds16((const char*)(Wl + (size_t)(o0 + row) * K + k0) + src_kb,
                        Ws + row * 128 + skb);
        }
#pragma unroll
        for (int r = 0; r < 8; ++r) {
            int row = srow + r * 32;
            gload_lds16((const char*)(xhB + (size_t)row * K + k0) + src_kb,
                        xhs + row * 128 + skb);
        }
        __syncthreads();
#pragma unroll
        for (int kk = 0; kk < 2; ++kk) {
            short8 b0[4];
#pragma unroll
            for (int j = 0; j < 4; ++j) {
                int row = wn * 64 + j * 16 + (lane & 15);
                int kb = ((((lane >> 4) * 8) + kk * 32) * 2) ^ ((row & 7) << 4);
                b0[j] = *(const short8*)(xhs + row * 128 + kb);
            }
#pragma unroll
            for (int i = 0; i < 8; ++i) {
                int row = i * 16 + (lane & 15);
                int kb = ((((lane >> 4) * 8) + kk * 32) * 2) ^ ((row & 7) << 4);
                short8 al = *(const short8*)(Ws + row * 128 + kb);
#pragma unroll
                for (int j = 0; j < 4; ++j)
                    acc[i][j] = __builtin_amdgcn_mfma_f32_16x16x32_bf16(
                        al, b0[j], acc[i][j], 0, 0, 0);
            }
        }
        __syncthreads();
    }

    LIF_EPILOGUE(pool, acc, 1024)
}

// ---------------- layer-2: 2-plane GEMM (whole-t block) + fused LIF ---------------
// S2[b][t][o] = LIF(Wh·S1 + Wl·S1 + bias).  Tile 128(o) x 256(t), 4 waves, BK=64.
// LDS 64KB: Ah 16K + Al 16K + B 32K -> 2 blocks/CU.  128 MFMA/step, B staged once.
__global__ __launch_bounds__(256) void gemm_lif2(
    const __hip_bfloat16* __restrict__ Ah, const __hip_bfloat16* __restrict__ Al,
    const __hip_bfloat16* __restrict__ B,
    const float* __restrict__ bias, __hip_bfloat16* __restrict__ Sout,
    const float* __restrict__ beta_p, const float* __restrict__ thr_p, int nOx) {
    const int K = 1024;
    __shared__ __align__(16) char pool[65536];
    char* Ahs = pool;            // 16KB
    char* Als = pool + 16384;    // 16KB
    char* Bs  = pool + 32768;    // 32KB (256 rows)

    const int fid = blockIdx.x;
    const int xcd = fid & 7;
    const int k_in = fid >> 3;
    const int b = xcd * 8 + k_in / nOx;
    const int o0 = (k_in % nOx) * 128;

    const int tid = threadIdx.x;
    const int lane = tid & 63;
    const int wn = tid >> 6;

    f32x4 acc[8][4] = {};

    const int srow = tid >> 3;
    const int skb  = (tid & 7) * 16;
    const int src_kb = skb ^ ((srow & 7) << 4);

    const __hip_bfloat16* Bb = B + (size_t)b * T_DIM * K;

    for (int k0 = 0; k0 < K; k0 += 64) {
#pragma unroll
        for (int r = 0; r < 4; ++r) {
            int row = srow + r * 32;
            gload_lds16((const char*)(Ah + (size_t)(o0 + row) * K + k0) + src_kb,
                        Ahs + row * 128 + skb);
            gload_lds16((const char*)(Al + (size_t)(o0 + row) * K + k0) + src_kb,
                        Als + row * 128 + skb);
        }
#pragma unroll
        for (int r = 0; r < 8; ++r) {
            int row = srow + r * 32;
            gload_lds16((const char*)(Bb + (size_t)row * K + k0) + src_kb,
                        Bs + row * 128 + skb);
        }
        __syncthreads();
#pragma unroll
        for (int kk = 0; kk < 2; ++kk) {
            short8 bfr[4];
#pragma unroll
            for (int j = 0; j < 4; ++j) {
                int row = wn * 64 + j * 16 + (lane & 15);
                int kb = ((((lane >> 4) * 8) + kk * 32) * 2) ^ ((row & 7) << 4);
                bfr[j] = *(const short8*)(Bs + row * 128 + kb);
            }
#pragma unroll
            for (int i = 0; i < 8; ++i) {
                int row = i * 16 + (lane & 15);
                int kb = ((((lane >> 4) * 8) + kk * 32) * 2) ^ ((row & 7) << 4);
                short8 ah = *(const short8*)(Ahs + row * 128 + kb);
                short8 al = *(const short8*)(Als + row * 128 + kb);
#pragma unroll
                for (int j = 0; j < 4; ++j)
                    acc[i][j] = __builtin_amdgcn_mfma_f32_16x16x32_bf16(
                        ah, bfr[j], acc[i][j], 0, 0, 0);
#pragma unroll
                for (int j = 0; j < 4; ++j)
                    acc[i][j] = __builtin_amdgcn_mfma_f32_16x16x32_bf16(
                        al, bfr[j], acc[i][j], 0, 0, 0);
            }
        }
        __syncthreads();
    }

    LIF_EPILOGUE(pool, acc, 1024)
}

// ---------------- layer-3 GEMM: two A planes share one staged B (round-9) ---------
template <int BN>
__global__ __launch_bounds__(256) void gemm_2a1b(
    const __hip_bfloat16* __restrict__ Ah, const __hip_bfloat16* __restrict__ Al,
    const __hip_bfloat16* __restrict__ B,
    const float* __restrict__ bias, float* __restrict__ Cout,
    int O, int K, int nOx, int nTy) {
    constexpr int NB = BN / 32;
    __shared__ __hip_bfloat16 Ash[128 * 64];
    __shared__ __hip_bfloat16 Asl[128 * 64];
    __shared__ __hip_bfloat16 Bs[BN * 64];

    const int fid = blockIdx.x;
    const int bpb = nOx * nTy;
    const int xcd = fid & 7;
    const int k_in = fid >> 3;
    const int b = xcd * 8 + k_in / bpb;
    const int r_in = k_in % bpb;
    const int o0 = (r_in / nTy) * 128;
    const int t0 = (r_in % nTy) * BN;

    const int tid = threadIdx.x;
    const int lane = tid & 63;
    const int wave = tid >> 6;
    const int wm = wave >> 1, wn = wave & 1;

    f32x4 acc[4][NB] = {};

    const int srow = tid >> 3;
    const int skb  = (tid & 7) * 16;
    const int src_kb = skb ^ ((srow & 7) << 4);

    const __hip_bfloat16* Bb = B + (size_t)b * T_DIM * K;

    for (int k0 = 0; k0 < K; k0 += 64) {
#pragma unroll
        for (int r = 0; r < 4; ++r) {
            int row = srow + r * 32;
            gload_lds16((const char*)(Ah + (size_t)(o0 + row) * K + k0) + src_kb,
                        (char*)Ash + row * 128 + skb);
            gload_lds16((const char*)(Al + (size_t)(o0 + row) * K + k0) + src_kb,
                        (char*)Asl + row * 128 + skb);
        }
#pragma unroll
        for (int r = 0; r < NB; ++r) {
            int row = srow + r * 32;
            gload_lds16((const char*)(Bb + (size_t)(t0 + row) * K + k0) + src_kb,
                        (char*)Bs + row * 128 + skb);
        }
        __syncthreads();
#pragma unroll
        for (int kk = 0; kk < 2; ++kk) {
            short8 afh[4], afl[4], bfr[NB];
#pragma unroll
            for (int i = 0; i < 4; ++i) {
                int row = wm * 64 + i * 16 + (lane & 15);
                int kb = ((((lane >> 4) * 8) + kk * 32) * 2) ^ ((row & 7) << 4);
                afh[i] = *(const short8*)((const char*)Ash + row * 128 + kb);
                afl[i] = *(const short8*)((const char*)Asl + row * 128 + kb);
            }
#pragma unroll
            for (int j = 0; j < NB; ++j) {
                int row = wn * (BN / 2) + j * 16 + (lane & 15);
                int kb = ((((lane >> 4) * 8) + kk * 32) * 2) ^ ((row & 7) << 4);
                bfr[j] = *(const short8*)((const char*)Bs + row * 128 + kb);
            }
#pragma unroll
            for (int i = 0; i < 4; ++i)
#pragma unroll
                for (int j = 0; j < NB; ++j)
                    acc[i][j] = __builtin_amdgcn_mfma_f32_16x16x32_bf16(
                        afh[i], bfr[j], acc[i][j], 0, 0, 0);
#pragma unroll
            for (int i = 0; i < 4; ++i)
#pragma unroll
                for (int j = 0; j < NB; ++j)
                    acc[i][j] = __builtin_amdgcn_mfma_f32_16x16x32_bf16(
                        afl[i], bfr[j], acc[i][j], 0, 0, 0);
        }
        __syncthreads();
    }
#pragma unroll
    for (int i = 0; i < 4; ++i) {
        int ob = o0 + wm * 64 + i * 16 + ((lane >> 4) * 4);
        f32x4 bv = *(const f32x4*)(bias + ob);
#pragma unroll
        for (int j = 0; j < NB; ++j) {
            int t = t0 + wn * (BN / 2) + j * 16 + (lane & 15);
            f32x4 v = acc[i][j] + bv;
            *(f32x4*)(Cout + ((size_t)b * T_DIM + t) * O + ob) = v;
        }
    }
}

// ---------------- LIF scan: final layer (LDS-transposed coalesced writes) ---------
__global__ __launch_bounds__(64) void lif_final_t(
    const float* __restrict__ pre, float* __restrict__ osp, float* __restrict__ omem,
    const float* __restrict__ beta_p, const float* __restrict__ thr_p) {
    __shared__ float spk[64][33];
    __shared__ float mm[64][33];
    int bid = blockIdx.x;
    int b = bid >> 2, og = bid & 3;
    int lane = threadIdx.x;
    float sb = 1.f / (1.f + expf(-beta_p[0]));
    float thr = thr_p[0];
    float mem = 0.f;
    const float* src = pre + (size_t)b * T_DIM * 256 + og * 64 + lane;
    int bo = b * 256 + og * 64;
    for (int c = 0; c < 8; ++c) {
        int t0 = c * 32;
        float xv[32];
#pragma unroll
        for (int tt = 0; tt < 32; ++tt)
            xv[tt] = src[(size_t)(t0 + tt) * 256];
#pragma unroll
        for (int tt = 0; tt < 32; ++tt) {
            mm[lane][tt] = mem;
            float mu = __fadd_rn(__fmul_rn(sb, mem), xv[tt]);
            float spike = (mu >= thr) ? 1.f : 0.f;
            spk[lane][tt] = spike;
            mem = mu - spike * thr;
        }
#pragma unroll
        for (int it = 0; it < 32; ++it) {
            int row = (lane >> 5) + 2 * it;
            int col = lane & 31;
            size_t dst = ((size_t)bo + row) * T_DIM + t0 + col;
            osp[dst] = spk[row][col];
            omem[dst] = mm[row][col];
        }
    }
}

extern "C" void kernel_launch(void* const* d_in, const int* in_sizes, int n_in,
                              void* d_out, int out_size, void* d_ws, size_t ws_size,
                              hipStream_t stream) {
    const float* x  = (const float*)d_in[0];
    const float* W0 = (const float*)d_in[1];
    const float* W1 = (const float*)d_in[2];
    const float* W2 = (const float*)d_in[3];
    const float* beta = (const float*)d_in[4];
    const float* thr  = (const float*)d_in[5];
    float* out = (float*)d_out;

    char* ws = (char*)d_ws;
    size_t off = 0;
    auto alloc = [&](size_t bytes) {
        size_t r = off;
        off = (off + bytes + 255) & ~(size_t)255;
        return r;
    };
    __hip_bfloat16* w0h = (__hip_bfloat16*)(ws + alloc(1024 * 512 * 2));
    __hip_bfloat16* w0l = (__hip_bfloat16*)(ws + alloc(1024 * 512 * 2));
    float* b0 = (float*)(ws + alloc(1024 * 4));
    __hip_bfloat16* w1h = (__hip_bfloat16*)(ws + alloc(1024 * 1024 * 2));
    __hip_bfloat16* w1l = (__hip_bfloat16*)(ws + alloc(1024 * 1024 * 2));
    float* b1 = (float*)(ws + alloc(1024 * 4));
    __hip_bfloat16* w2h = (__hip_bfloat16*)(ws + alloc(256 * 1024 * 2));
    __hip_bfloat16* w2l = (__hip_bfloat16*)(ws + alloc(256 * 1024 * 2));
    float* b2 = (float*)(ws + alloc(256 * 4));
    __hip_bfloat16* xh = (__hip_bfloat16*)(ws + alloc((size_t)NBATCH * T_DIM * 512 * 2));
    __hip_bfloat16* xl = (__hip_bfloat16*)(ws + alloc((size_t)NBATCH * T_DIM * 512 * 2));
    __hip_bfloat16* S1 = (__hip_bfloat16*)(ws + alloc((size_t)NBATCH * T_DIM * 1024 * 2));
    __hip_bfloat16* S2 = (__hip_bfloat16*)(ws + alloc((size_t)NBATCH * T_DIM * 1024 * 2));
    float* pre = (float*)(ws + alloc((size_t)NBATCH * T_DIM * 256 * 4));
    (void)ws_size; (void)in_sizes; (void)n_in; (void)out_size;

    prep_w<<<(1024 * 512 + 255) / 256, 256, 0, stream>>>(W0, w0h, w0l, b0, 512, 1024);
    prep_w<<<(1024 * 1024 + 255) / 256, 256, 0, stream>>>(W1, w1h, w1l, b1, 1024, 1024);
    prep_w<<<(256 * 1024 + 255) / 256, 256, 0, stream>>>(W2, w2h, w2l, b2, 1024, 256);
    prep_x<<<dim3(16, 8, 64), dim3(32, 8), 0, stream>>>(x, xh, xl);

    // Layer 1: plane-fused whole-t GEMM + fused LIF; grid 512 = 2 blocks/CU
    gemm_lif_l1<<<dim3(512), 256, 0, stream>>>(w0h, w0l, xh, xl, b0, S1, beta, thr, 8);

    // Layer 2: 2-plane whole-t GEMM + fused LIF; grid 512
    gemm_lif2<<<dim3(512), 256, 0, stream>>>(w1h, w1l, S1, b1, S2, beta, thr, 8);

    // Layer 3: O=256, K=1024, BN=64 -> grid 512; then final LIF (writes d_out)
    gemm_2a1b<64><<<dim3(512), 256, 0, stream>>>(w2h, w2l, S2, b2, pre, 256, 1024, 2, 4);
    lif_final_t<<<dim3(256), 64, 0, stream>>>(pre, out, out + (size_t)NBATCH * 256 * T_DIM,
                                              beta, thr);
}

// Round 12
// 227.574 us; speedup vs baseline: 1.1041x; 1.1041x over previous
//
#include <hip/hip_runtime.h>
#include <hip/hip_bf16.h>
#include <stdint.h>

typedef __attribute__((ext_vector_type(8))) _Float16 half8;
typedef __attribute__((ext_vector_type(4))) float f32x4;

#define T_DIM 256
#define NBATCH 64

__device__ __forceinline__ void gload_lds16(const void* g, void* l) {
    __builtin_amdgcn_global_load_lds(
        (const __attribute__((address_space(1))) void*)g,
        (__attribute__((address_space(3))) void*)l, 16, 0, 0);
}

// ---- prep: W [(K+1)][O] fp32 -> fp16 hi/lo planes [O][K] (~22-bit W) + bias[O] ---
__global__ void prep_w2p(const float* __restrict__ W, _Float16* __restrict__ WTh,
                         _Float16* __restrict__ WTl, float* __restrict__ bias,
                         int K, int O) {
    int idx = blockIdx.x * blockDim.x + threadIdx.x;
    int total = O * K;
    if (idx < total) {
        int o = idx / K, i = idx % K;
        float w = W[(size_t)i * O + o];
        _Float16 h = (_Float16)w;
        WTh[idx] = h;
        WTl[idx] = (_Float16)(w - (float)h);
    }
    if (idx < O) bias[idx] = W[(size_t)K * O + idx];
}

// ---- prep: x [64][512][256] fp32 -> xf [64][256][512] fp16 -----------------------
__global__ void prep_x1p(const float* __restrict__ x, _Float16* __restrict__ xf) {
    __shared__ float tile[32][33];
    int b = blockIdx.z;
    int i0 = blockIdx.x * 32;
    int t0 = blockIdx.y * 32;
    int tx = threadIdx.x;
    int ty = threadIdx.y;
    for (int dy = 0; dy < 32; dy += 8)
        tile[ty + dy][tx] = x[((size_t)b * 512 + i0 + ty + dy) * T_DIM + t0 + tx];
    __syncthreads();
    for (int dy = 0; dy < 32; dy += 8) {
        float w = tile[tx][ty + dy];
        size_t dst = ((size_t)b * T_DIM + t0 + ty + dy) * 512 + i0 + tx;
        xf[dst] = (_Float16)w;
    }
}

// ---- fp16 GEMM: two A planes (hi/lo) share one staged B (round-9 proven shape) ---
// pre[b][t][o] = Ah[o][:]·B[b][t][:] + Al[o][:]·B[b][t][:] + bias[o].
// Tile 128(o) x BN(t), 4 waves (2M x 2N), BK=64, LDS 32KB+BN*128B, XCD mapping.
template <int BN>
__global__ __launch_bounds__(256) void gemm_f16_2a1b(
    const _Float16* __restrict__ Ah, const _Float16* __restrict__ Al,
    const _Float16* __restrict__ B,
    const float* __restrict__ bias, float* __restrict__ Cout,
    int O, int K, int nOx, int nTy) {
    constexpr int NB = BN / 32;
    __shared__ char Ash[128 * 128];
    __shared__ char Asl[128 * 128];
    __shared__ char Bs[BN * 128];

    const int fid = blockIdx.x;
    const int bpb = nOx * nTy;
    const int xcd = fid & 7;
    const int k_in = fid >> 3;
    const int b = xcd * 8 + k_in / bpb;
    const int r_in = k_in % bpb;
    const int o0 = (r_in / nTy) * 128;
    const int t0 = (r_in % nTy) * BN;

    const int tid = threadIdx.x;
    const int lane = tid & 63;
    const int wave = tid >> 6;
    const int wm = wave >> 1, wn = wave & 1;

    f32x4 acc[4][NB] = {};

    const int srow = tid >> 3;         // 0..31
    const int skb  = (tid & 7) * 16;
    const int src_kb = skb ^ ((srow & 7) << 4);

    const _Float16* Bb = B + (size_t)b * T_DIM * K;

    for (int k0 = 0; k0 < K; k0 += 64) {
#pragma unroll
        for (int r = 0; r < 4; ++r) {
            int row = srow + r * 32;
            gload_lds16((const char*)(Ah + (size_t)(o0 + row) * K + k0) + src_kb,
                        Ash + row * 128 + skb);
            gload_lds16((const char*)(Al + (size_t)(o0 + row) * K + k0) + src_kb,
                        Asl + row * 128 + skb);
        }
#pragma unroll
        for (int r = 0; r < NB; ++r) {
            int row = srow + r * 32;
            gload_lds16((const char*)(Bb + (size_t)(t0 + row) * K + k0) + src_kb,
                        Bs + row * 128 + skb);
        }
        __syncthreads();
#pragma unroll
        for (int kk = 0; kk < 2; ++kk) {
            half8 afh[4], afl[4], bfr[NB];
#pragma unroll
            for (int i = 0; i < 4; ++i) {
                int row = wm * 64 + i * 16 + (lane & 15);
                int kb = ((((lane >> 4) * 8) + kk * 32) * 2) ^ ((row & 7) << 4);
                afh[i] = *(const half8*)(Ash + row * 128 + kb);
                afl[i] = *(const half8*)(Asl + row * 128 + kb);
            }
#pragma unroll
            for (int j = 0; j < NB; ++j) {
                int row = wn * (BN / 2) + j * 16 + (lane & 15);
                int kb = ((((lane >> 4) * 8) + kk * 32) * 2) ^ ((row & 7) << 4);
                bfr[j] = *(const half8*)(Bs + row * 128 + kb);
            }
#pragma unroll
            for (int i = 0; i < 4; ++i)
#pragma unroll
                for (int j = 0; j < NB; ++j)
                    acc[i][j] = __builtin_amdgcn_mfma_f32_16x16x32_f16(
                        afh[i], bfr[j], acc[i][j], 0, 0, 0);
#pragma unroll
            for (int i = 0; i < 4; ++i)
#pragma unroll
                for (int j = 0; j < NB; ++j)
                    acc[i][j] = __builtin_amdgcn_mfma_f32_16x16x32_f16(
                        afl[i], bfr[j], acc[i][j], 0, 0, 0);
        }
        __syncthreads();
    }
    // epilogue: D col(t)=lane&15, row(o)=(lane>>4)*4+r -> float4/lane into [b][t][o]
#pragma unroll
    for (int i = 0; i < 4; ++i) {
        int ob = o0 + wm * 64 + i * 16 + ((lane >> 4) * 4);
        f32x4 bv = *(const f32x4*)(bias + ob);
#pragma unroll
        for (int j = 0; j < NB; ++j) {
            int t = t0 + wn * (BN / 2) + j * 16 + (lane & 15);
            f32x4 v = acc[i][j] + bv;
            *(f32x4*)(Cout + ((size_t)b * T_DIM + t) * O + ob) = v;
        }
    }
}

// ---- LIF scan: hidden layers; spikes written as exact fp16 ones (0x3C00) ---------
__global__ void lif_hidden(const float* __restrict__ pre, unsigned short* __restrict__ st,
                           const float* __restrict__ beta_p, const float* __restrict__ thr_p,
                           int O) {
    int idx = blockIdx.x * blockDim.x + threadIdx.x;
    int b = idx / O, o = idx - b * O;
    float sb = 1.f / (1.f + expf(-beta_p[0]));
    float thr = thr_p[0];
    float mem = 0.f;
    const float* src = pre + (size_t)b * T_DIM * O + o;
    unsigned short* dst = st + (size_t)b * T_DIM * O + o;
    for (int t = 0; t < T_DIM; ++t) {
        float mu = __fadd_rn(__fmul_rn(sb, mem), src[(size_t)t * O]);
        float spike = (mu >= thr) ? 1.f : 0.f;
        mem = mu - spike * thr;
        dst[(size_t)t * O] = (mu >= thr) ? (unsigned short)0x3C00 : (unsigned short)0;
    }
}

// ---- LIF scan: final layer (LDS-transposed coalesced writes) ----------------------
__global__ __launch_bounds__(64) void lif_final_t(
    const float* __restrict__ pre, float* __restrict__ osp, float* __restrict__ omem,
    const float* __restrict__ beta_p, const float* __restrict__ thr_p) {
    __shared__ float spk[64][33];
    __shared__ float mm[64][33];
    int bid = blockIdx.x;
    int b = bid >> 2, og = bid & 3;
    int lane = threadIdx.x;
    float sb = 1.f / (1.f + expf(-beta_p[0]));
    float thr = thr_p[0];
    float mem = 0.f;
    const float* src = pre + (size_t)b * T_DIM * 256 + og * 64 + lane;
    int bo = b * 256 + og * 64;
    for (int c = 0; c < 8; ++c) {
        int t0 = c * 32;
        float xv[32];
#pragma unroll
        for (int tt = 0; tt < 32; ++tt)
            xv[tt] = src[(size_t)(t0 + tt) * 256];
#pragma unroll
        for (int tt = 0; tt < 32; ++tt) {
            mm[lane][tt] = mem;
            float mu = __fadd_rn(__fmul_rn(sb, mem), xv[tt]);
            float spike = (mu >= thr) ? 1.f : 0.f;
            spk[lane][tt] = spike;
            mem = mu - spike * thr;
        }
#pragma unroll
        for (int it = 0; it < 32; ++it) {
            int row = (lane >> 5) + 2 * it;
            int col = lane & 31;
            size_t dst = ((size_t)bo + row) * T_DIM + t0 + col;
            osp[dst] = spk[row][col];
            omem[dst] = mm[row][col];
        }
    }
}

extern "C" void kernel_launch(void* const* d_in, const int* in_sizes, int n_in,
                              void* d_out, int out_size, void* d_ws, size_t ws_size,
                              hipStream_t stream) {
    const float* x  = (const float*)d_in[0];
    const float* W0 = (const float*)d_in[1];
    const float* W1 = (const float*)d_in[2];
    const float* W2 = (const float*)d_in[3];
    const float* beta = (const float*)d_in[4];
    const float* thr  = (const float*)d_in[5];
    float* out = (float*)d_out;

    char* ws = (char*)d_ws;
    size_t off = 0;
    auto alloc = [&](size_t bytes) {
        size_t r = off;
        off = (off + bytes + 255) & ~(size_t)255;
        return r;
    };
    _Float16* w0h = (_Float16*)(ws + alloc(1024 * 512 * 2));
    _Float16* w0l = (_Float16*)(ws + alloc(1024 * 512 * 2));
    float* b0 = (float*)(ws + alloc(1024 * 4));
    _Float16* w1h = (_Float16*)(ws + alloc(1024 * 1024 * 2));
    _Float16* w1l = (_Float16*)(ws + alloc(1024 * 1024 * 2));
    float* b1 = (float*)(ws + alloc(1024 * 4));
    _Float16* w2h = (_Float16*)(ws + alloc(256 * 1024 * 2));
    _Float16* w2l = (_Float16*)(ws + alloc(256 * 1024 * 2));
    float* b2 = (float*)(ws + alloc(256 * 4));
    _Float16* xf = (_Float16*)(ws + alloc((size_t)NBATCH * T_DIM * 512 * 2));
    unsigned short* S1 = (unsigned short*)(ws + alloc((size_t)NBATCH * T_DIM * 1024 * 2));
    unsigned short* S2 = (unsigned short*)(ws + alloc((size_t)NBATCH * T_DIM * 1024 * 2));
    float* pre = (float*)(ws + alloc((size_t)NBATCH * T_DIM * 1024 * 4));
    float* pre3 = (float*)(ws + alloc((size_t)NBATCH * T_DIM * 256 * 4));
    (void)ws_size; (void)in_sizes; (void)n_in; (void)out_size;

    prep_w2p<<<(1024 * 512 + 255) / 256, 256, 0, stream>>>(W0, w0h, w0l, b0, 512, 1024);
    prep_w2p<<<(1024 * 1024 + 255) / 256, 256, 0, stream>>>(W1, w1h, w1l, b1, 1024, 1024);
    prep_w2p<<<(256 * 1024 + 255) / 256, 256, 0, stream>>>(W2, w2h, w2l, b2, 1024, 256);
    prep_x1p<<<dim3(16, 8, 64), dim3(32, 8), 0, stream>>>(x, xf);

    // Layer 1: fp16 (Wh+Wl)·xf, K=512, x staged once; grid 64*16
    gemm_f16_2a1b<128><<<dim3(1024), 256, 0, stream>>>(w0h, w0l, xf, b0, pre,
                                                       1024, 512, 8, 2);
    lif_hidden<<<(NBATCH * 1024) / 256, 256, 0, stream>>>(pre, S1, beta, thr, 1024);

    // Layer 2: fp16 (Wh+Wl)·S1 (spikes exact in fp16), K=1024
    gemm_f16_2a1b<128><<<dim3(1024), 256, 0, stream>>>(w1h, w1l, (const _Float16*)S1,
                                                       b1, pre, 1024, 1024, 8, 2);
    lif_hidden<<<(NBATCH * 1024) / 256, 256, 0, stream>>>(pre, S2, beta, thr, 1024);

    // Layer 3: fp16 (Wh+Wl)·S2, K=1024, BN=64 -> grid 512
    gemm_f16_2a1b<64><<<dim3(512), 256, 0, stream>>>(w2h, w2l, (const _Float16*)S2,
                                                     b2, pre3, 256, 1024, 2, 4);
    lif_final_t<<<dim3(256), 64, 0, stream>>>(pre3, out, out + (size_t)NBATCH * 256 * T_DIM,
                                              beta, thr);
}

// Round 13
// 194.068 us; speedup vs baseline: 1.2947x; 1.1727x over previous
//
#include <hip/hip_runtime.h>
#include <hip/hip_bf16.h>
#include <stdint.h>

typedef __attribute__((ext_vector_type(8))) _Float16 half8;
typedef __attribute__((ext_vector_type(4))) float f32x4;

#define T_DIM 256
#define NBATCH 64

__device__ __forceinline__ void gload_lds16(const void* g, void* l) {
    __builtin_amdgcn_global_load_lds(
        (const __attribute__((address_space(1))) void*)g,
        (__attribute__((address_space(3))) void*)l, 16, 0, 0);
}

// ---- prep: W [(K+1)][O] fp32 -> fp16 hi/lo planes [O][K] (~22-bit W) + bias[O] ---
__global__ void prep_w2p(const float* __restrict__ W, _Float16* __restrict__ WTh,
                         _Float16* __restrict__ WTl, float* __restrict__ bias,
                         int K, int O) {
    int idx = blockIdx.x * blockDim.x + threadIdx.x;
    int total = O * K;
    if (idx < total) {
        int o = idx / K, i = idx % K;
        float w = W[(size_t)i * O + o];
        _Float16 h = (_Float16)w;
        WTh[idx] = h;
        WTl[idx] = (_Float16)(w - (float)h);
    }
    if (idx < O) bias[idx] = W[(size_t)K * O + idx];
}

// ---- prep: x [64][512][256] fp32 -> xf [64][256][512] fp16 -----------------------
__global__ void prep_x1p(const float* __restrict__ x, _Float16* __restrict__ xf) {
    __shared__ float tile[32][33];
    int b = blockIdx.z;
    int i0 = blockIdx.x * 32;
    int t0 = blockIdx.y * 32;
    int tx = threadIdx.x;
    int ty = threadIdx.y;
    for (int dy = 0; dy < 32; dy += 8)
        tile[ty + dy][tx] = x[((size_t)b * 512 + i0 + ty + dy) * T_DIM + t0 + tx];
    __syncthreads();
    for (int dy = 0; dy < 32; dy += 8) {
        float w = tile[tx][ty + dy];
        size_t dst = ((size_t)b * T_DIM + t0 + ty + dy) * 512 + i0 + tx;
        xf[dst] = (_Float16)w;
    }
}

// ---- hidden-layer fused GEMM+LIF: 64(o) x 256(t) tile, 4 waves (1M x 4N) ----------
// S[b][t][o] = LIF(Ah·B + Al·B + bias).  Per-wave inner loop identical to the
// proven r12 BN=128 kernel (12 ds_read + 32 MFMA per kk, 12 gload/k-step),
// acc[4][4] (64 VGPR), LDS 48KB -> 3 blocks/CU, independent blocks.
// Wave wn owns t in [wn*64, wn*64+64) -> LIF in-epilogue: 4 chunks dumped to LDS
// [64t][68o] fp32, 64 threads scan with mem in registers.  Accumulation order and
// LIF math bit-identical to r12's unfused path (absmax canary 2.5).
__global__ __launch_bounds__(256) void gemm_f16_lif(
    const _Float16* __restrict__ Ah, const _Float16* __restrict__ Al,
    const _Float16* __restrict__ B,
    const float* __restrict__ bias, unsigned short* __restrict__ Sout,
    const float* __restrict__ beta_p, const float* __restrict__ thr_p,
    int O, int K) {
    __shared__ __align__(16) char pool[49152];
    char* Ash = pool;            // 64 x 128B = 8KB
    char* Asl = pool + 8192;     // 8KB
    char* Bs  = pool + 16384;    // 256 x 128B = 32KB

    const int nOx = O >> 6;
    const int fid = blockIdx.x;
    const int xcd = fid & 7;
    const int k_in = fid >> 3;
    const int b = xcd * 8 + k_in / nOx;
    const int o0 = (k_in % nOx) * 64;

    const int tid = threadIdx.x;
    const int lane = tid & 63;
    const int wn = tid >> 6;           // wave = t-quarter

    f32x4 acc[4][4] = {};

    const int srow = tid >> 3;         // 0..31
    const int skb  = (tid & 7) * 16;
    const int src_kb = skb ^ ((srow & 7) << 4);

    const _Float16* Bb = B + (size_t)b * T_DIM * K;

    for (int k0 = 0; k0 < K; k0 += 64) {
#pragma unroll
        for (int r = 0; r < 2; ++r) {
            int row = srow + r * 32;   // 0..63
            gload_lds16((const char*)(Ah + (size_t)(o0 + row) * K + k0) + src_kb,
                        Ash + row * 128 + skb);
            gload_lds16((const char*)(Al + (size_t)(o0 + row) * K + k0) + src_kb,
                        Asl + row * 128 + skb);
        }
#pragma unroll
        for (int r = 0; r < 8; ++r) {
            int row = srow + r * 32;   // 0..255
            gload_lds16((const char*)(Bb + (size_t)row * K + k0) + src_kb,
                        Bs + row * 128 + skb);
        }
        __syncthreads();
#pragma unroll
        for (int kk = 0; kk < 2; ++kk) {
            half8 afh[4], afl[4], bfr[4];
#pragma unroll
            for (int i = 0; i < 4; ++i) {
                int row = i * 16 + (lane & 15);
                int kb = ((((lane >> 4) * 8) + kk * 32) * 2) ^ ((row & 7) << 4);
                afh[i] = *(const half8*)(Ash + row * 128 + kb);
                afl[i] = *(const half8*)(Asl + row * 128 + kb);
            }
#pragma unroll
            for (int j = 0; j < 4; ++j) {
                int row = wn * 64 + j * 16 + (lane & 15);
                int kb = ((((lane >> 4) * 8) + kk * 32) * 2) ^ ((row & 7) << 4);
                bfr[j] = *(const half8*)(Bs + row * 128 + kb);
            }
#pragma unroll
            for (int i = 0; i < 4; ++i)
#pragma unroll
                for (int j = 0; j < 4; ++j)
                    acc[i][j] = __builtin_amdgcn_mfma_f32_16x16x32_f16(
                        afh[i], bfr[j], acc[i][j], 0, 0, 0);
#pragma unroll
            for (int i = 0; i < 4; ++i)
#pragma unroll
                for (int j = 0; j < 4; ++j)
                    acc[i][j] = __builtin_amdgcn_mfma_f32_16x16x32_f16(
                        afl[i], bfr[j], acc[i][j], 0, 0, 0);
        }
        __syncthreads();
    }

    // ---- fused LIF epilogue: 4 chunks of 64 t; mem carried in wave-0 registers ----
    float sb = 1.f / (1.f + expf(-beta_p[0]));
    float thrv = thr_p[0];
    float* fpool = (float*)pool;       // [64 t][68 o] fp32 = 17.4KB (aliases Ash/Asl)
    float mem = 0.f;
    for (int tc = 0; tc < 4; ++tc) {
        __syncthreads();               // pool free / previous chunk consumed
        if (wn == tc) {
            // D layout: col(t)=lane&15, row(o)=(lane>>4)*4+r
#pragma unroll
            for (int i = 0; i < 4; ++i) {
                int o = i * 16 + ((lane >> 4) * 4);
                f32x4 bv = *(const f32x4*)(bias + o0 + o);
#pragma unroll
                for (int j = 0; j < 4; ++j) {
                    int tl = j * 16 + (lane & 15);
                    *(f32x4*)(fpool + tl * 68 + o) = acc[i][j] + bv;
                }
            }
        }
        __syncthreads();
        if (tid < 64) {
#pragma unroll 4
            for (int tt = 0; tt < 64; ++tt) {
                float mu = __fadd_rn(__fmul_rn(sb, mem), fpool[tt * 68 + tid]);
                float spike = (mu >= thrv) ? 1.f : 0.f;
                mem = mu - spike * thrv;
                Sout[((size_t)b * T_DIM + tc * 64 + tt) * O + o0 + tid] =
                    (mu >= thrv) ? (unsigned short)0x3C00 : (unsigned short)0;
            }
        }
    }
}

// ---- fp16 GEMM: two A planes (hi/lo) share one staged B (layer 3, proven) --------
template <int BN>
__global__ __launch_bounds__(256) void gemm_f16_2a1b(
    const _Float16* __restrict__ Ah, const _Float16* __restrict__ Al,
    const _Float16* __restrict__ B,
    const float* __restrict__ bias, float* __restrict__ Cout,
    int O, int K, int nOx, int nTy) {
    constexpr int NB = BN / 32;
    __shared__ char Ash[128 * 128];
    __shared__ char Asl[128 * 128];
    __shared__ char Bs[BN * 128];

    const int fid = blockIdx.x;
    const int bpb = nOx * nTy;
    const int xcd = fid & 7;
    const int k_in = fid >> 3;
    const int b = xcd * 8 + k_in / bpb;
    const int r_in = k_in % bpb;
    const int o0 = (r_in / nTy) * 128;
    const int t0 = (r_in % nTy) * BN;

    const int tid = threadIdx.x;
    const int lane = tid & 63;
    const int wave = tid >> 6;
    const int wm = wave >> 1, wn = wave & 1;

    f32x4 acc[4][NB] = {};

    const int srow = tid >> 3;
    const int skb  = (tid & 7) * 16;
    const int src_kb = skb ^ ((srow & 7) << 4);

    const _Float16* Bb = B + (size_t)b * T_DIM * K;

    for (int k0 = 0; k0 < K; k0 += 64) {
#pragma unroll
        for (int r = 0; r < 4; ++r) {
            int row = srow + r * 32;
            gload_lds16((const char*)(Ah + (size_t)(o0 + row) * K + k0) + src_kb,
                        Ash + row * 128 + skb);
            gload_lds16((const char*)(Al + (size_t)(o0 + row) * K + k0) + src_kb,
                        Asl + row * 128 + skb);
        }
#pragma unroll
        for (int r = 0; r < NB; ++r) {
            int row = srow + r * 32;
            gload_lds16((const char*)(Bb + (size_t)(t0 + row) * K + k0) + src_kb,
                        Bs + row * 128 + skb);
        }
        __syncthreads();
#pragma unroll
        for (int kk = 0; kk < 2; ++kk) {
            half8 afh[4], afl[4], bfr[NB];
#pragma unroll
            for (int i = 0; i < 4; ++i) {
                int row = wm * 64 + i * 16 + (lane & 15);
                int kb = ((((lane >> 4) * 8) + kk * 32) * 2) ^ ((row & 7) << 4);
                afh[i] = *(const half8*)(Ash + row * 128 + kb);
                afl[i] = *(const half8*)(Asl + row * 128 + kb);
            }
#pragma unroll
            for (int j = 0; j < NB; ++j) {
                int row = wn * (BN / 2) + j * 16 + (lane & 15);
                int kb = ((((lane >> 4) * 8) + kk * 32) * 2) ^ ((row & 7) << 4);
                bfr[j] = *(const half8*)(Bs + row * 128 + kb);
            }
#pragma unroll
            for (int i = 0; i < 4; ++i)
#pragma unroll
                for (int j = 0; j < NB; ++j)
                    acc[i][j] = __builtin_amdgcn_mfma_f32_16x16x32_f16(
                        afh[i], bfr[j], acc[i][j], 0, 0, 0);
#pragma unroll
            for (int i = 0; i < 4; ++i)
#pragma unroll
                for (int j = 0; j < NB; ++j)
                    acc[i][j] = __builtin_amdgcn_mfma_f32_16x16x32_f16(
                        afl[i], bfr[j], acc[i][j], 0, 0, 0);
        }
        __syncthreads();
    }
#pragma unroll
    for (int i = 0; i < 4; ++i) {
        int ob = o0 + wm * 64 + i * 16 + ((lane >> 4) * 4);
        f32x4 bv = *(const f32x4*)(bias + ob);
#pragma unroll
        for (int j = 0; j < NB; ++j) {
            int t = t0 + wn * (BN / 2) + j * 16 + (lane & 15);
            f32x4 v = acc[i][j] + bv;
            *(f32x4*)(Cout + ((size_t)b * T_DIM + t) * O + ob) = v;
        }
    }
}

// ---- LIF scan: final layer (LDS-transposed coalesced writes) ----------------------
__global__ __launch_bounds__(64) void lif_final_t(
    const float* __restrict__ pre, float* __restrict__ osp, float* __restrict__ omem,
    const float* __restrict__ beta_p, const float* __restrict__ thr_p) {
    __shared__ float spk[64][33];
    __shared__ float mm[64][33];
    int bid = blockIdx.x;
    int b = bid >> 2, og = bid & 3;
    int lane = threadIdx.x;
    float sb = 1.f / (1.f + expf(-beta_p[0]));
    float thr = thr_p[0];
    float mem = 0.f;
    const float* src = pre + (size_t)b * T_DIM * 256 + og * 64 + lane;
    int bo = b * 256 + og * 64;
    for (int c = 0; c < 8; ++c) {
        int t0 = c * 32;
        float xv[32];
#pragma unroll
        for (int tt = 0; tt < 32; ++tt)
            xv[tt] = src[(size_t)(t0 + tt) * 256];
#pragma unroll
        for (int tt = 0; tt < 32; ++tt) {
            mm[lane][tt] = mem;
            float mu = __fadd_rn(__fmul_rn(sb, mem), xv[tt]);
            float spike = (mu >= thr) ? 1.f : 0.f;
            spk[lane][tt] = spike;
            mem = mu - spike * thr;
        }
#pragma unroll
        for (int it = 0; it < 32; ++it) {
            int row = (lane >> 5) + 2 * it;
            int col = lane & 31;
            size_t dst = ((size_t)bo + row) * T_DIM + t0 + col;
            osp[dst] = spk[row][col];
            omem[dst] = mm[row][col];
        }
    }
}

extern "C" void kernel_launch(void* const* d_in, const int* in_sizes, int n_in,
                              void* d_out, int out_size, void* d_ws, size_t ws_size,
                              hipStream_t stream) {
    const float* x  = (const float*)d_in[0];
    const float* W0 = (const float*)d_in[1];
    const float* W1 = (const float*)d_in[2];
    const float* W2 = (const float*)d_in[3];
    const float* beta = (const float*)d_in[4];
    const float* thr  = (const float*)d_in[5];
    float* out = (float*)d_out;

    char* ws = (char*)d_ws;
    size_t off = 0;
    auto alloc = [&](size_t bytes) {
        size_t r = off;
        off = (off + bytes + 255) & ~(size_t)255;
        return r;
    };
    _Float16* w0h = (_Float16*)(ws + alloc(1024 * 512 * 2));
    _Float16* w0l = (_Float16*)(ws + alloc(1024 * 512 * 2));
    float* b0 = (float*)(ws + alloc(1024 * 4));
    _Float16* w1h = (_Float16*)(ws + alloc(1024 * 1024 * 2));
    _Float16* w1l = (_Float16*)(ws + alloc(1024 * 1024 * 2));
    float* b1 = (float*)(ws + alloc(1024 * 4));
    _Float16* w2h = (_Float16*)(ws + alloc(256 * 1024 * 2));
    _Float16* w2l = (_Float16*)(ws + alloc(256 * 1024 * 2));
    float* b2 = (float*)(ws + alloc(256 * 4));
    _Float16* xf = (_Float16*)(ws + alloc((size_t)NBATCH * T_DIM * 512 * 2));
    unsigned short* S1 = (unsigned short*)(ws + alloc((size_t)NBATCH * T_DIM * 1024 * 2));
    unsigned short* S2 = (unsigned short*)(ws + alloc((size_t)NBATCH * T_DIM * 1024 * 2));
    float* pre3 = (float*)(ws + alloc((size_t)NBATCH * T_DIM * 256 * 4));
    (void)ws_size; (void)in_sizes; (void)n_in; (void)out_size;

    prep_w2p<<<(1024 * 512 + 255) / 256, 256, 0, stream>>>(W0, w0h, w0l, b0, 512, 1024);
    prep_w2p<<<(1024 * 1024 + 255) / 256, 256, 0, stream>>>(W1, w1h, w1l, b1, 1024, 1024);
    prep_w2p<<<(256 * 1024 + 255) / 256, 256, 0, stream>>>(W2, w2h, w2l, b2, 1024, 256);
    prep_x1p<<<dim3(16, 8, 64), dim3(32, 8), 0, stream>>>(x, xf);

    // Layer 1: fused fp16 GEMM+LIF, K=512; grid 64*16 = 1024 (3 blocks/CU wave)
    gemm_f16_lif<<<dim3(1024), 256, 0, stream>>>(w0h, w0l, xf, b0, S1, beta, thr,
                                                 1024, 512);
    // Layer 2: fused fp16 GEMM+LIF, K=1024 (B = S1 spikes, exact fp16)
    gemm_f16_lif<<<dim3(1024), 256, 0, stream>>>(w1h, w1l, (const _Float16*)S1,
                                                 b1, S2, beta, thr, 1024, 1024);
    // Layer 3: fp16 (Wh+Wl)·S2, K=1024, BN=64 -> grid 512; then final LIF
    gemm_f16_2a1b<64><<<dim3(512), 256, 0, stream>>>(w2h, w2l, (const _Float16*)S2,
                                                     b2, pre3, 256, 1024, 2, 4);
    lif_final_t<<<dim3(256), 64, 0, stream>>>(pre3, out, out + (size_t)NBATCH * 256 * T_DIM,
                                              beta, thr);
}

// Round 14
// 178.148 us; speedup vs baseline: 1.4104x; 1.0894x over previous
//
#include <hip/hip_runtime.h>
#include <hip/hip_bf16.h>
#include <stdint.h>

typedef __attribute__((ext_vector_type(8))) _Float16 half8;
typedef __attribute__((ext_vector_type(4))) float f32x4;

#define T_DIM 256
#define NBATCH 64

__device__ __forceinline__ void gload_lds16(const void* g, void* l) {
    __builtin_amdgcn_global_load_lds(
        (const __attribute__((address_space(1))) void*)g,
        (__attribute__((address_space(3))) void*)l, 16, 0, 0);
}

// ---- prep: W [(K+1)][O] fp32 -> fp16 hi(/lo) planes [O][K] + bias[O] -------------
// LDS-tiled transpose: both global reads and writes coalesced (was 4KB-stride
// scatter reads).  WTl == nullptr -> single-plane (hi only).
__global__ void prep_wT(const float* __restrict__ W, _Float16* __restrict__ WTh,
                        _Float16* __restrict__ WTl, float* __restrict__ bias,
                        int K, int O) {
    __shared__ float tile[32][33];
    int i0 = blockIdx.x * 32;   // K dim
    int o0 = blockIdx.y * 32;   // O dim
    int tx = threadIdx.x;       // 0..31
    int ty = threadIdx.y;       // 0..7
    for (int dy = 0; dy < 32; dy += 8)
        tile[ty + dy][tx] = W[(size_t)(i0 + ty + dy) * O + o0 + tx];
    if (blockIdx.x == 0 && ty == 0)
        bias[o0 + tx] = W[(size_t)K * O + o0 + tx];
    __syncthreads();
    for (int dy = 0; dy < 32; dy += 8) {
        float w = tile[tx][ty + dy];             // W[i0+tx][o0+ty+dy]
        size_t dst = (size_t)(o0 + ty + dy) * K + i0 + tx;
        _Float16 h = (_Float16)w;
        WTh[dst] = h;
        if (WTl) WTl[dst] = (_Float16)(w - (float)h);
    }
}

// ---- prep: x [64][512][256] fp32 -> xf [64][256][512] fp16 -----------------------
__global__ void prep_x1p(const float* __restrict__ x, _Float16* __restrict__ xf) {
    __shared__ float tile[32][33];
    int b = blockIdx.z;
    int i0 = blockIdx.x * 32;
    int t0 = blockIdx.y * 32;
    int tx = threadIdx.x;
    int ty = threadIdx.y;
    for (int dy = 0; dy < 32; dy += 8)
        tile[ty + dy][tx] = x[((size_t)b * 512 + i0 + ty + dy) * T_DIM + t0 + tx];
    __syncthreads();
    for (int dy = 0; dy < 32; dy += 8) {
        float w = tile[tx][ty + dy];
        size_t dst = ((size_t)b * T_DIM + t0 + ty + dy) * 512 + i0 + tx;
        xf[dst] = (_Float16)w;
    }
}

// ---- hidden-layer fused GEMM+LIF: 64(o) x 256(t) tile, 4 waves (1M x 4N) ----------
// S[b][t][o] = LIF(sum_planes A_p·B + bias).  NP=2: hi+lo planes (L1, 48KB LDS,
// 3 blocks/CU).  NP=1: single plane (L2, 40KB LDS, 4 blocks/CU).  Per-wave inner
// loop = proven r12 structure.  acc[4][4], independent blocks, XCD mapping.
// LIF epilogue: 4 chunks of 64 t dumped to LDS [64t][68o], 64 threads scan with
// mem carried in registers.
template <int NP>
__global__ __launch_bounds__(256) void gemm_f16_lif(
    const _Float16* __restrict__ Ah, const _Float16* __restrict__ Al,
    const _Float16* __restrict__ B,
    const float* __restrict__ bias, unsigned short* __restrict__ Sout,
    const float* __restrict__ beta_p, const float* __restrict__ thr_p,
    int O, int K) {
    __shared__ __align__(16) char pool[NP == 2 ? 49152 : 40960];
    char* Ash = pool;                  // 64 x 128B = 8KB
    char* Asl = pool + 8192;           // 8KB (NP==2 only)
    char* Bs  = pool + NP * 8192;      // 256 x 128B = 32KB

    const int nOx = O >> 6;
    const int fid = blockIdx.x;
    const int xcd = fid & 7;
    const int k_in = fid >> 3;
    const int b = xcd * 8 + k_in / nOx;
    const int o0 = (k_in % nOx) * 64;

    const int tid = threadIdx.x;
    const int lane = tid & 63;
    const int wn = tid >> 6;           // wave = t-quarter

    f32x4 acc[4][4] = {};

    const int srow = tid >> 3;         // 0..31
    const int skb  = (tid & 7) * 16;
    const int src_kb = skb ^ ((srow & 7) << 4);

    const _Float16* Bb = B + (size_t)b * T_DIM * K;

    for (int k0 = 0; k0 < K; k0 += 64) {
#pragma unroll
        for (int r = 0; r < 2; ++r) {
            int row = srow + r * 32;   // 0..63
            gload_lds16((const char*)(Ah + (size_t)(o0 + row) * K + k0) + src_kb,
                        Ash + row * 128 + skb);
            if (NP == 2)
                gload_lds16((const char*)(Al + (size_t)(o0 + row) * K + k0) + src_kb,
                            Asl + row * 128 + skb);
        }
#pragma unroll
        for (int r = 0; r < 8; ++r) {
            int row = srow + r * 32;   // 0..255
            gload_lds16((const char*)(Bb + (size_t)row * K + k0) + src_kb,
                        Bs + row * 128 + skb);
        }
        __syncthreads();
#pragma unroll
        for (int kk = 0; kk < 2; ++kk) {
            half8 afh[4], afl[4], bfr[4];
#pragma unroll
            for (int i = 0; i < 4; ++i) {
                int row = i * 16 + (lane & 15);
                int kb = ((((lane >> 4) * 8) + kk * 32) * 2) ^ ((row & 7) << 4);
                afh[i] = *(const half8*)(Ash + row * 128 + kb);
                if (NP == 2) afl[i] = *(const half8*)(Asl + row * 128 + kb);
            }
#pragma unroll
            for (int j = 0; j < 4; ++j) {
                int row = wn * 64 + j * 16 + (lane & 15);
                int kb = ((((lane >> 4) * 8) + kk * 32) * 2) ^ ((row & 7) << 4);
                bfr[j] = *(const half8*)(Bs + row * 128 + kb);
            }
#pragma unroll
            for (int i = 0; i < 4; ++i)
#pragma unroll
                for (int j = 0; j < 4; ++j)
                    acc[i][j] = __builtin_amdgcn_mfma_f32_16x16x32_f16(
                        afh[i], bfr[j], acc[i][j], 0, 0, 0);
            if (NP == 2) {
#pragma unroll
                for (int i = 0; i < 4; ++i)
#pragma unroll
                    for (int j = 0; j < 4; ++j)
                        acc[i][j] = __builtin_amdgcn_mfma_f32_16x16x32_f16(
                            afl[i], bfr[j], acc[i][j], 0, 0, 0);
            }
        }
        __syncthreads();
    }

    // ---- fused LIF epilogue ----
    float sb = 1.f / (1.f + expf(-beta_p[0]));
    float thrv = thr_p[0];
    float* fpool = (float*)pool;       // [64 t][68 o] fp32 = 17.4KB
    float mem = 0.f;
    for (int tc = 0; tc < 4; ++tc) {
        __syncthreads();
        if (wn == tc) {
            // D layout: col(t)=lane&15, row(o)=(lane>>4)*4+r
#pragma unroll
            for (int i = 0; i < 4; ++i) {
                int o = i * 16 + ((lane >> 4) * 4);
                f32x4 bv = *(const f32x4*)(bias + o0 + o);
#pragma unroll
                for (int j = 0; j < 4; ++j) {
                    int tl = j * 16 + (lane & 15);
                    *(f32x4*)(fpool + tl * 68 + o) = acc[i][j] + bv;
                }
            }
        }
        __syncthreads();
        if (tid < 64) {
#pragma unroll 4
            for (int tt = 0; tt < 64; ++tt) {
                float mu = __fadd_rn(__fmul_rn(sb, mem), fpool[tt * 68 + tid]);
                float spike = (mu >= thrv) ? 1.f : 0.f;
                mem = mu - spike * thrv;
                Sout[((size_t)b * T_DIM + tc * 64 + tt) * O + o0 + tid] =
                    (mu >= thrv) ? (unsigned short)0x3C00 : (unsigned short)0;
            }
        }
    }
}

// ---- fp16 GEMM: two A planes (hi/lo) share one staged B (layer 3, proven) --------
template <int BN>
__global__ __launch_bounds__(256) void gemm_f16_2a1b(
    const _Float16* __restrict__ Ah, const _Float16* __restrict__ Al,
    const _Float16* __restrict__ B,
    const float* __restrict__ bias, float* __restrict__ Cout,
    int O, int K, int nOx, int nTy) {
    constexpr int NB = BN / 32;
    __shared__ char Ash[128 * 128];
    __shared__ char Asl[128 * 128];
    __shared__ char Bs[BN * 128];

    const int fid = blockIdx.x;
    const int bpb = nOx * nTy;
    const int xcd = fid & 7;
    const int k_in = fid >> 3;
    const int b = xcd * 8 + k_in / bpb;
    const int r_in = k_in % bpb;
    const int o0 = (r_in / nTy) * 128;
    const int t0 = (r_in % nTy) * BN;

    const int tid = threadIdx.x;
    const int lane = tid & 63;
    const int wave = tid >> 6;
    const int wm = wave >> 1, wn = wave & 1;

    f32x4 acc[4][NB] = {};

    const int srow = tid >> 3;
    const int skb  = (tid & 7) * 16;
    const int src_kb = skb ^ ((srow & 7) << 4);

    const _Float16* Bb = B + (size_t)b * T_DIM * K;

    for (int k0 = 0; k0 < K; k0 += 64) {
#pragma unroll
        for (int r = 0; r < 4; ++r) {
            int row = srow + r * 32;
            gload_lds16((const char*)(Ah + (size_t)(o0 + row) * K + k0) + src_kb,
                        Ash + row * 128 + skb);
            gload_lds16((const char*)(Al + (size_t)(o0 + row) * K + k0) + src_kb,
                        Asl + row * 128 + skb);
        }
#pragma unroll
        for (int r = 0; r < NB; ++r) {
            int row = srow + r * 32;
            gload_lds16((const char*)(Bb + (size_t)(t0 + row) * K + k0) + src_kb,
                        Bs + row * 128 + skb);
        }
        __syncthreads();
#pragma unroll
        for (int kk = 0; kk < 2; ++kk) {
            half8 afh[4], afl[4], bfr[NB];
#pragma unroll
            for (int i = 0; i < 4; ++i) {
                int row = wm * 64 + i * 16 + (lane & 15);
                int kb = ((((lane >> 4) * 8) + kk * 32) * 2) ^ ((row & 7) << 4);
                afh[i] = *(const half8*)(Ash + row * 128 + kb);
                afl[i] = *(const half8*)(Asl + row * 128 + kb);
            }
#pragma unroll
            for (int j = 0; j < NB; ++j) {
                int row = wn * (BN / 2) + j * 16 + (lane & 15);
                int kb = ((((lane >> 4) * 8) + kk * 32) * 2) ^ ((row & 7) << 4);
                bfr[j] = *(const half8*)(Bs + row * 128 + kb);
            }
#pragma unroll
            for (int i = 0; i < 4; ++i)
#pragma unroll
                for (int j = 0; j < NB; ++j)
                    acc[i][j] = __builtin_amdgcn_mfma_f32_16x16x32_f16(
                        afh[i], bfr[j], acc[i][j], 0, 0, 0);
#pragma unroll
            for (int i = 0; i < 4; ++i)
#pragma unroll
                for (int j = 0; j < NB; ++j)
                    acc[i][j] = __builtin_amdgcn_mfma_f32_16x16x32_f16(
                        afl[i], bfr[j], acc[i][j], 0, 0, 0);
        }
        __syncthreads();
    }
#pragma unroll
    for (int i = 0; i < 4; ++i) {
        int ob = o0 + wm * 64 + i * 16 + ((lane >> 4) * 4);
        f32x4 bv = *(const f32x4*)(bias + ob);
#pragma unroll
        for (int j = 0; j < NB; ++j) {
            int t = t0 + wn * (BN / 2) + j * 16 + (lane & 15);
            f32x4 v = acc[i][j] + bv;
            *(f32x4*)(Cout + ((size_t)b * T_DIM + t) * O + ob) = v;
        }
    }
}

// ---- LIF scan: final layer (LDS-transposed coalesced writes) ----------------------
__global__ __launch_bounds__(64) void lif_final_t(
    const float* __restrict__ pre, float* __restrict__ osp, float* __restrict__ omem,
    const float* __restrict__ beta_p, const float* __restrict__ thr_p) {
    __shared__ float spk[64][33];
    __shared__ float mm[64][33];
    int bid = blockIdx.x;
    int b = bid >> 2, og = bid & 3;
    int lane = threadIdx.x;
    float sb = 1.f / (1.f + expf(-beta_p[0]));
    float thr = thr_p[0];
    float mem = 0.f;
    const float* src = pre + (size_t)b * T_DIM * 256 + og * 64 + lane;
    int bo = b * 256 + og * 64;
    for (int c = 0; c < 8; ++c) {
        int t0 = c * 32;
        float xv[32];
#pragma unroll
        for (int tt = 0; tt < 32; ++tt)
            xv[tt] = src[(size_t)(t0 + tt) * 256];
#pragma unroll
        for (int tt = 0; tt < 32; ++tt) {
            mm[lane][tt] = mem;
            float mu = __fadd_rn(__fmul_rn(sb, mem), xv[tt]);
            float spike = (mu >= thr) ? 1.f : 0.f;
            spk[lane][tt] = spike;
            mem = mu - spike * thr;
        }
#pragma unroll
        for (int it = 0; it < 32; ++it) {
            int row = (lane >> 5) + 2 * it;
            int col = lane & 31;
            size_t dst = ((size_t)bo + row) * T_DIM + t0 + col;
            osp[dst] = spk[row][col];
            omem[dst] = mm[row][col];
        }
    }
}

extern "C" void kernel_launch(void* const* d_in, const int* in_sizes, int n_in,
                              void* d_out, int out_size, void* d_ws, size_t ws_size,
                              hipStream_t stream) {
    const float* x  = (const float*)d_in[0];
    const float* W0 = (const float*)d_in[1];
    const float* W1 = (const float*)d_in[2];
    const float* W2 = (const float*)d_in[3];
    const float* beta = (const float*)d_in[4];
    const float* thr  = (const float*)d_in[5];
    float* out = (float*)d_out;

    char* ws = (char*)d_ws;
    size_t off = 0;
    auto alloc = [&](size_t bytes) {
        size_t r = off;
        off = (off + bytes + 255) & ~(size_t)255;
        return r;
    };
    _Float16* w0h = (_Float16*)(ws + alloc(1024 * 512 * 2));
    _Float16* w0l = (_Float16*)(ws + alloc(1024 * 512 * 2));
    float* b0 = (float*)(ws + alloc(1024 * 4));
    _Float16* w1f = (_Float16*)(ws + alloc(1024 * 1024 * 2));
    float* b1 = (float*)(ws + alloc(1024 * 4));
    _Float16* w2h = (_Float16*)(ws + alloc(256 * 1024 * 2));
    _Float16* w2l = (_Float16*)(ws + alloc(256 * 1024 * 2));
    float* b2 = (float*)(ws + alloc(256 * 4));
    _Float16* xf = (_Float16*)(ws + alloc((size_t)NBATCH * T_DIM * 512 * 2));
    unsigned short* S1 = (unsigned short*)(ws + alloc((size_t)NBATCH * T_DIM * 1024 * 2));
    unsigned short* S2 = (unsigned short*)(ws + alloc((size_t)NBATCH * T_DIM * 1024 * 2));
    float* pre3 = (float*)(ws + alloc((size_t)NBATCH * T_DIM * 256 * 4));
    (void)ws_size; (void)in_sizes; (void)n_in; (void)out_size;

    // W preps: LDS-tiled transpose (coalesced both sides)
    prep_wT<<<dim3(16, 32), dim3(32, 8), 0, stream>>>(W0, w0h, w0l, b0, 512, 1024);
    prep_wT<<<dim3(32, 32), dim3(32, 8), 0, stream>>>(W1, w1f, nullptr, b1, 1024, 1024);
    prep_wT<<<dim3(32, 8),  dim3(32, 8), 0, stream>>>(W2, w2h, w2l, b2, 1024, 256);
    prep_x1p<<<dim3(16, 8, 64), dim3(32, 8), 0, stream>>>(x, xf);

    // Layer 1: fused fp16 GEMM+LIF, 2 planes, K=512; grid 1024 (3 blocks/CU)
    gemm_f16_lif<2><<<dim3(1024), 256, 0, stream>>>(w0h, w0l, xf, b0, S1, beta, thr,
                                                    1024, 512);
    // Layer 2: fused fp16 GEMM+LIF, SINGLE plane, K=1024; 40KB LDS -> 4 blocks/CU
    gemm_f16_lif<1><<<dim3(1024), 256, 0, stream>>>(w1f, nullptr, (const _Float16*)S1,
                                                    b1, S2, beta, thr, 1024, 1024);
    // Layer 3: fp16 (Wh+Wl)·S2 (2-plane, guards output-mem precision), BN=64
    gemm_f16_2a1b<64><<<dim3(512), 256, 0, stream>>>(w2h, w2l, (const _Float16*)S2,
                                                     b2, pre3, 256, 1024, 2, 4);
    lif_final_t<<<dim3(256), 64, 0, stream>>>(pre3, out, out + (size_t)NBATCH * 256 * T_DIM,
                                              beta, thr);
}

// Round 15
// 154.117 us; speedup vs baseline: 1.6303x; 1.1559x over previous
//
#include <hip/hip_runtime.h>
#include <hip/hip_bf16.h>
#include <stdint.h>

typedef __attribute__((ext_vector_type(8))) _Float16 half8;
typedef __attribute__((ext_vector_type(4))) float f32x4;

#define T_DIM 256
#define NBATCH 64

__device__ __forceinline__ void gload_lds16(const void* g, void* l) {
    __builtin_amdgcn_global_load_lds(
        (const __attribute__((address_space(1))) void*)g,
        (__attribute__((address_space(3))) void*)l, 16, 0, 0);
}

// ---- prep: W [(K+1)][O] fp32 -> fp16 hi(/lo) planes [O][K] + bias[O] -------------
__global__ void prep_wT(const float* __restrict__ W, _Float16* __restrict__ WTh,
                        _Float16* __restrict__ WTl, float* __restrict__ bias,
                        int K, int O) {
    __shared__ float tile[32][33];
    int i0 = blockIdx.x * 32;   // K dim
    int o0 = blockIdx.y * 32;   // O dim
    int tx = threadIdx.x;       // 0..31
    int ty = threadIdx.y;       // 0..7
    for (int dy = 0; dy < 32; dy += 8)
        tile[ty + dy][tx] = W[(size_t)(i0 + ty + dy) * O + o0 + tx];
    if (blockIdx.x == 0 && ty == 0)
        bias[o0 + tx] = W[(size_t)K * O + o0 + tx];
    __syncthreads();
    for (int dy = 0; dy < 32; dy += 8) {
        float w = tile[tx][ty + dy];             // W[i0+tx][o0+ty+dy]
        size_t dst = (size_t)(o0 + ty + dy) * K + i0 + tx;
        _Float16 h = (_Float16)w;
        WTh[dst] = h;
        if (WTl) WTl[dst] = (_Float16)(w - (float)h);
    }
}

// ---- prep: x [64][512][256] fp32 -> xf [64][256][512] fp16 -----------------------
__global__ void prep_x1p(const float* __restrict__ x, _Float16* __restrict__ xf) {
    __shared__ float tile[32][33];
    int b = blockIdx.z;
    int i0 = blockIdx.x * 32;
    int t0 = blockIdx.y * 32;
    int tx = threadIdx.x;
    int ty = threadIdx.y;
    for (int dy = 0; dy < 32; dy += 8)
        tile[ty + dy][tx] = x[((size_t)b * 512 + i0 + ty + dy) * T_DIM + t0 + tx];
    __syncthreads();
    for (int dy = 0; dy < 32; dy += 8) {
        float w = tile[tx][ty + dy];
        size_t dst = ((size_t)b * T_DIM + t0 + ty + dy) * 512 + i0 + tx;
        xf[dst] = (_Float16)w;
    }
}

// ---- L1 fused GEMM+LIF: 64(o) x 256(t), 4 waves (1M x 4N), 2 planes (r14 proven) --
template <int NP>
__global__ __launch_bounds__(256) void gemm_f16_lif(
    const _Float16* __restrict__ Ah, const _Float16* __restrict__ Al,
    const _Float16* __restrict__ B,
    const float* __restrict__ bias, unsigned short* __restrict__ Sout,
    const float* __restrict__ beta_p, const float* __restrict__ thr_p,
    int O, int K) {
    __shared__ __align__(16) char pool[NP == 2 ? 49152 : 40960];
    char* Ash = pool;                  // 64 x 128B = 8KB
    char* Asl = pool + 8192;           // 8KB (NP==2 only)
    char* Bs  = pool + NP * 8192;      // 256 x 128B = 32KB

    const int nOx = O >> 6;
    const int fid = blockIdx.x;
    const int xcd = fid & 7;
    const int k_in = fid >> 3;
    const int b = xcd * 8 + k_in / nOx;
    const int o0 = (k_in % nOx) * 64;

    const int tid = threadIdx.x;
    const int lane = tid & 63;
    const int wn = tid >> 6;           // wave = t-quarter

    f32x4 acc[4][4] = {};

    const int srow = tid >> 3;         // 0..31
    const int skb  = (tid & 7) * 16;
    const int src_kb = skb ^ ((srow & 7) << 4);

    const _Float16* Bb = B + (size_t)b * T_DIM * K;

    for (int k0 = 0; k0 < K; k0 += 64) {
#pragma unroll
        for (int r = 0; r < 2; ++r) {
            int row = srow + r * 32;   // 0..63
            gload_lds16((const char*)(Ah + (size_t)(o0 + row) * K + k0) + src_kb,
                        Ash + row * 128 + skb);
            if (NP == 2)
                gload_lds16((const char*)(Al + (size_t)(o0 + row) * K + k0) + src_kb,
                            Asl + row * 128 + skb);
        }
#pragma unroll
        for (int r = 0; r < 8; ++r) {
            int row = srow + r * 32;   // 0..255
            gload_lds16((const char*)(Bb + (size_t)row * K + k0) + src_kb,
                        Bs + row * 128 + skb);
        }
        __syncthreads();
#pragma unroll
        for (int kk = 0; kk < 2; ++kk) {
            half8 afh[4], afl[4], bfr[4];
#pragma unroll
            for (int i = 0; i < 4; ++i) {
                int row = i * 16 + (lane & 15);
                int kb = ((((lane >> 4) * 8) + kk * 32) * 2) ^ ((row & 7) << 4);
                afh[i] = *(const half8*)(Ash + row * 128 + kb);
                if (NP == 2) afl[i] = *(const half8*)(Asl + row * 128 + kb);
            }
#pragma unroll
            for (int j = 0; j < 4; ++j) {
                int row = wn * 64 + j * 16 + (lane & 15);
                int kb = ((((lane >> 4) * 8) + kk * 32) * 2) ^ ((row & 7) << 4);
                bfr[j] = *(const half8*)(Bs + row * 128 + kb);
            }
#pragma unroll
            for (int i = 0; i < 4; ++i)
#pragma unroll
                for (int j = 0; j < 4; ++j)
                    acc[i][j] = __builtin_amdgcn_mfma_f32_16x16x32_f16(
                        afh[i], bfr[j], acc[i][j], 0, 0, 0);
            if (NP == 2) {
#pragma unroll
                for (int i = 0; i < 4; ++i)
#pragma unroll
                    for (int j = 0; j < 4; ++j)
                        acc[i][j] = __builtin_amdgcn_mfma_f32_16x16x32_f16(
                            afl[i], bfr[j], acc[i][j], 0, 0, 0);
            }
        }
        __syncthreads();
    }

    // ---- fused LIF epilogue ----
    float sb = 1.f / (1.f + expf(-beta_p[0]));
    float thrv = thr_p[0];
    float* fpool = (float*)pool;       // [64 t][68 o] fp32 = 17.4KB
    float mem = 0.f;
    for (int tc = 0; tc < 4; ++tc) {
        __syncthreads();
        if (wn == tc) {
            // D layout: col(t)=lane&15, row(o)=(lane>>4)*4+r
#pragma unroll
            for (int i = 0; i < 4; ++i) {
                int o = i * 16 + ((lane >> 4) * 4);
                f32x4 bv = *(const f32x4*)(bias + o0 + o);
#pragma unroll
                for (int j = 0; j < 4; ++j) {
                    int tl = j * 16 + (lane & 15);
                    *(f32x4*)(fpool + tl * 68 + o) = acc[i][j] + bv;
                }
            }
        }
        __syncthreads();
        if (tid < 64) {
#pragma unroll 4
            for (int tt = 0; tt < 64; ++tt) {
                float mu = __fadd_rn(__fmul_rn(sb, mem), fpool[tt * 68 + tid]);
                float spike = (mu >= thrv) ? 1.f : 0.f;
                mem = mu - spike * thrv;
                Sout[((size_t)b * T_DIM + tc * 64 + tt) * O + o0 + tid] =
                    (mu >= thrv) ? (unsigned short)0x3C00 : (unsigned short)0;
            }
        }
    }
}

// ---- L2 fused GEMM+LIF: 128(o) x 256(t), 8 waves (2M x 4N), single plane ----------
// Per-wave inner loop identical to the proven shape (16 ds_read + 32 MFMA per
// k-step, acc[4][4] = 64 VGPR).  LDS 48KB (A 16K + B 32K) -> 3 blocks/CU =
// 24 waves/CU.  Staging: 6 gloads/thread/k-step (was 10); B staged by 8 blocks
// per batch (was 16).  Accumulation order per output element identical to r14's
// NP=1 path -> bit-identical (absmax canary 2.585938).
__global__ __launch_bounds__(512) void gemm_f16_lif8(
    const _Float16* __restrict__ A, const _Float16* __restrict__ B,
    const float* __restrict__ bias, unsigned short* __restrict__ Sout,
    const float* __restrict__ beta_p, const float* __restrict__ thr_p,
    int O, int K) {
    __shared__ __align__(16) char pool[49152];
    char* Ash = pool;                  // 128 x 128B = 16KB
    char* Bs  = pool + 16384;          // 256 x 128B = 32KB

    const int nOx = O >> 7;            // o-groups of 128
    const int fid = blockIdx.x;
    const int xcd = fid & 7;
    const int k_in = fid >> 3;
    const int b = xcd * 8 + k_in / nOx;
    const int o0 = (k_in % nOx) * 128;

    const int tid = threadIdx.x;
    const int lane = tid & 63;
    const int wave = tid >> 6;         // 0..7
    const int wm = wave >> 2;          // 0..1 (o half)
    const int wn = wave & 3;           // 0..3 (t quarter)

    f32x4 acc[4][4] = {};

    const int srow = tid >> 3;         // 0..63
    const int skb  = (tid & 7) * 16;
    const int src_kb = skb ^ ((srow & 7) << 4);

    const _Float16* Bb = B + (size_t)b * T_DIM * K;

    for (int k0 = 0; k0 < K; k0 += 64) {
#pragma unroll
        for (int r = 0; r < 2; ++r) {
            int row = srow + r * 64;   // 0..127
            gload_lds16((const char*)(A + (size_t)(o0 + row) * K + k0) + src_kb,
                        Ash + row * 128 + skb);
        }
#pragma unroll
        for (int r = 0; r < 4; ++r) {
            int row = srow + r * 64;   // 0..255
            gload_lds16((const char*)(Bb + (size_t)row * K + k0) + src_kb,
                        Bs + row * 128 + skb);
        }
        __syncthreads();
#pragma unroll
        for (int kk = 0; kk < 2; ++kk) {
            half8 af[4], bfr[4];
#pragma unroll
            for (int i = 0; i < 4; ++i) {
                int row = wm * 64 + i * 16 + (lane & 15);
                int kb = ((((lane >> 4) * 8) + kk * 32) * 2) ^ ((row & 7) << 4);
                af[i] = *(const half8*)(Ash + row * 128 + kb);
            }
#pragma unroll
            for (int j = 0; j < 4; ++j) {
                int row = wn * 64 + j * 16 + (lane & 15);
                int kb = ((((lane >> 4) * 8) + kk * 32) * 2) ^ ((row & 7) << 4);
                bfr[j] = *(const half8*)(Bs + row * 128 + kb);
            }
#pragma unroll
            for (int i = 0; i < 4; ++i)
#pragma unroll
                for (int j = 0; j < 4; ++j)
                    acc[i][j] = __builtin_amdgcn_mfma_f32_16x16x32_f16(
                        af[i], bfr[j], acc[i][j], 0, 0, 0);
        }
        __syncthreads();
    }

    // ---- fused LIF epilogue: 4 chunks of 64 t; fpool [64t][132o] = 33.8KB ---------
    float sb = 1.f / (1.f + expf(-beta_p[0]));
    float thrv = thr_p[0];
    float* fpool = (float*)pool;
    float mem = 0.f;
    for (int tc = 0; tc < 4; ++tc) {
        __syncthreads();
        if (wn == tc) {                // two waves (wm = 0,1) dump this chunk
#pragma unroll
            for (int i = 0; i < 4; ++i) {
                int o = wm * 64 + i * 16 + ((lane >> 4) * 4);
                f32x4 bv = *(const f32x4*)(bias + o0 + o);
#pragma unroll
                for (int j = 0; j < 4; ++j) {
                    int tl = j * 16 + (lane & 15);
                    *(f32x4*)(fpool + tl * 132 + o) = acc[i][j] + bv;
                }
            }
        }
        __syncthreads();
        if (tid < 128) {
#pragma unroll 4
            for (int tt = 0; tt < 64; ++tt) {
                float mu = __fadd_rn(__fmul_rn(sb, mem), fpool[tt * 132 + tid]);
                float spike = (mu >= thrv) ? 1.f : 0.f;
                mem = mu - spike * thrv;
                Sout[((size_t)b * T_DIM + tc * 64 + tt) * O + o0 + tid] =
                    (mu >= thrv) ? (unsigned short)0x3C00 : (unsigned short)0;
            }
        }
    }
}

// ---- fp16 GEMM: two A planes (hi/lo) share one staged B (layer 3, proven) --------
template <int BN>
__global__ __launch_bounds__(256) void gemm_f16_2a1b(
    const _Float16* __restrict__ Ah, const _Float16* __restrict__ Al,
    const _Float16* __restrict__ B,
    const float* __restrict__ bias, float* __restrict__ Cout,
    int O, int K, int nOx, int nTy) {
    constexpr int NB = BN / 32;
    __shared__ char Ash[128 * 128];
    __shared__ char Asl[128 * 128];
    __shared__ char Bs[BN * 128];

    const int fid = blockIdx.x;
    const int bpb = nOx * nTy;
    const int xcd = fid & 7;
    const int k_in = fid >> 3;
    const int b = xcd * 8 + k_in / bpb;
    const int r_in = k_in % bpb;
    const int o0 = (r_in / nTy) * 128;
    const int t0 = (r_in % nTy) * BN;

    const int tid = threadIdx.x;
    const int lane = tid & 63;
    const int wave = tid >> 6;
    const int wm = wave >> 1, wn = wave & 1;

    f32x4 acc[4][NB] = {};

    const int srow = tid >> 3;
    const int skb  = (tid & 7) * 16;
    const int src_kb = skb ^ ((srow & 7) << 4);

    const _Float16* Bb = B + (size_t)b * T_DIM * K;

    for (int k0 = 0; k0 < K; k0 += 64) {
#pragma unroll
        for (int r = 0; r < 4; ++r) {
            int row = srow + r * 32;
            gload_lds16((const char*)(Ah + (size_t)(o0 + row) * K + k0) + src_kb,
                        Ash + row * 128 + skb);
            gload_lds16((const char*)(Al + (size_t)(o0 + row) * K + k0) + src_kb,
                        Asl + row * 128 + skb);
        }
#pragma unroll
        for (int r = 0; r < NB; ++r) {
            int row = srow + r * 32;
            gload_lds16((const char*)(Bb + (size_t)(t0 + row) * K + k0) + src_kb,
                        Bs + row * 128 + skb);
        }
        __syncthreads();
#pragma unroll
        for (int kk = 0; kk < 2; ++kk) {
            half8 afh[4], afl[4], bfr[NB];
#pragma unroll
            for (int i = 0; i < 4; ++i) {
                int row = wm * 64 + i * 16 + (lane & 15);
                int kb = ((((lane >> 4) * 8) + kk * 32) * 2) ^ ((row & 7) << 4);
                afh[i] = *(const half8*)(Ash + row * 128 + kb);
                afl[i] = *(const half8*)(Asl + row * 128 + kb);
            }
#pragma unroll
            for (int j = 0; j < NB; ++j) {
                int row = wn * (BN / 2) + j * 16 + (lane & 15);
                int kb = ((((lane >> 4) * 8) + kk * 32) * 2) ^ ((row & 7) << 4);
                bfr[j] = *(const half8*)(Bs + row * 128 + kb);
            }
#pragma unroll
            for (int i = 0; i < 4; ++i)
#pragma unroll
                for (int j = 0; j < NB; ++j)
                    acc[i][j] = __builtin_amdgcn_mfma_f32_16x16x32_f16(
                        afh[i], bfr[j], acc[i][j], 0, 0, 0);
#pragma unroll
            for (int i = 0; i < 4; ++i)
#pragma unroll
                for (int j = 0; j < NB; ++j)
                    acc[i][j] = __builtin_amdgcn_mfma_f32_16x16x32_f16(
                        afl[i], bfr[j], acc[i][j], 0, 0, 0);
        }
        __syncthreads();
    }
#pragma unroll
    for (int i = 0; i < 4; ++i) {
        int ob = o0 + wm * 64 + i * 16 + ((lane >> 4) * 4);
        f32x4 bv = *(const f32x4*)(bias + ob);
#pragma unroll
        for (int j = 0; j < NB; ++j) {
            int t = t0 + wn * (BN / 2) + j * 16 + (lane & 15);
            f32x4 v = acc[i][j] + bv;
            *(f32x4*)(Cout + ((size_t)b * T_DIM + t) * O + ob) = v;
        }
    }
}

// ---- LIF scan: final layer (LDS-transposed coalesced writes) ----------------------
__global__ __launch_bounds__(64) void lif_final_t(
    const float* __restrict__ pre, float* __restrict__ osp, float* __restrict__ omem,
    const float* __restrict__ beta_p, const float* __restrict__ thr_p) {
    __shared__ float spk[64][33];
    __shared__ float mm[64][33];
    int bid = blockIdx.x;
    int b = bid >> 2, og = bid & 3;
    int lane = threadIdx.x;
    float sb = 1.f / (1.f + expf(-beta_p[0]));
    float thr = thr_p[0];
    float mem = 0.f;
    const float* src = pre + (size_t)b * T_DIM * 256 + og * 64 + lane;
    int bo = b * 256 + og * 64;
    for (int c = 0; c < 8; ++c) {
        int t0 = c * 32;
        float xv[32];
#pragma unroll
        for (int tt = 0; tt < 32; ++tt)
            xv[tt] = src[(size_t)(t0 + tt) * 256];
#pragma unroll
        for (int tt = 0; tt < 32; ++tt) {
            mm[lane][tt] = mem;
            float mu = __fadd_rn(__fmul_rn(sb, mem), xv[tt]);
            float spike = (mu >= thr) ? 1.f : 0.f;
            spk[lane][tt] = spike;
            mem = mu - spike * thr;
        }
#pragma unroll
        for (int it = 0; it < 32; ++it) {
            int row = (lane >> 5) + 2 * it;
            int col = lane & 31;
            size_t dst = ((size_t)bo + row) * T_DIM + t0 + col;
            osp[dst] = spk[row][col];
            omem[dst] = mm[row][col];
        }
    }
}

extern "C" void kernel_launch(void* const* d_in, const int* in_sizes, int n_in,
                              void* d_out, int out_size, void* d_ws, size_t ws_size,
                              hipStream_t stream) {
    const float* x  = (const float*)d_in[0];
    const float* W0 = (const float*)d_in[1];
    const float* W1 = (const float*)d_in[2];
    const float* W2 = (const float*)d_in[3];
    const float* beta = (const float*)d_in[4];
    const float* thr  = (const float*)d_in[5];
    float* out = (float*)d_out;

    char* ws = (char*)d_ws;
    size_t off = 0;
    auto alloc = [&](size_t bytes) {
        size_t r = off;
        off = (off + bytes + 255) & ~(size_t)255;
        return r;
    };
    _Float16* w0h = (_Float16*)(ws + alloc(1024 * 512 * 2));
    _Float16* w0l = (_Float16*)(ws + alloc(1024 * 512 * 2));
    float* b0 = (float*)(ws + alloc(1024 * 4));
    _Float16* w1f = (_Float16*)(ws + alloc(1024 * 1024 * 2));
    float* b1 = (float*)(ws + alloc(1024 * 4));
    _Float16* w2h = (_Float16*)(ws + alloc(256 * 1024 * 2));
    _Float16* w2l = (_Float16*)(ws + alloc(256 * 1024 * 2));
    float* b2 = (float*)(ws + alloc(256 * 4));
    _Float16* xf = (_Float16*)(ws + alloc((size_t)NBATCH * T_DIM * 512 * 2));
    unsigned short* S1 = (unsigned short*)(ws + alloc((size_t)NBATCH * T_DIM * 1024 * 2));
    unsigned short* S2 = (unsigned short*)(ws + alloc((size_t)NBATCH * T_DIM * 1024 * 2));
    float* pre3 = (float*)(ws + alloc((size_t)NBATCH * T_DIM * 256 * 4));
    (void)ws_size; (void)in_sizes; (void)n_in; (void)out_size;

    // W preps: LDS-tiled transpose (coalesced both sides)
    prep_wT<<<dim3(16, 32), dim3(32, 8), 0, stream>>>(W0, w0h, w0l, b0, 512, 1024);
    prep_wT<<<dim3(32, 32), dim3(32, 8), 0, stream>>>(W1, w1f, nullptr, b1, 1024, 1024);
    prep_wT<<<dim3(32, 8),  dim3(32, 8), 0, stream>>>(W2, w2h, w2l, b2, 1024, 256);
    prep_x1p<<<dim3(16, 8, 64), dim3(32, 8), 0, stream>>>(x, xf);

    // Layer 1: fused fp16 GEMM+LIF, 2 planes, 64x256 tile (r14 proven); grid 1024
    gemm_f16_lif<2><<<dim3(1024), 256, 0, stream>>>(w0h, w0l, xf, b0, S1, beta, thr,
                                                    1024, 512);
    // Layer 2: fused fp16 GEMM+LIF, single plane, 128x256 tile, 8 waves; grid 512
    gemm_f16_lif8<<<dim3(512), 512, 0, stream>>>(w1f, (const _Float16*)S1,
                                                 b1, S2, beta, thr, 1024, 1024);
    // Layer 3: fp16 (Wh+Wl)·S2 (2-plane, guards output-mem precision), BN=64
    gemm_f16_2a1b<64><<<dim3(512), 256, 0, stream>>>(w2h, w2l, (const _Float16*)S2,
                                                     b2, pre3, 256, 1024, 2, 4);
    lif_final_t<<<dim3(256), 64, 0, stream>>>(pre3, out, out + (size_t)NBATCH * 256 * T_DIM,
                                              beta, thr);
}

// Round 16
// 142.770 us; speedup vs baseline: 1.7599x; 1.0795x over previous
//
#include <hip/hip_runtime.h>
#include <hip/hip_bf16.h>
#include <stdint.h>

typedef __attribute__((ext_vector_type(8))) _Float16 half8;
typedef __attribute__((ext_vector_type(4))) float f32x4;

#define T_DIM 256
#define NBATCH 64

__device__ __forceinline__ void gload_lds16(const void* g, void* l) {
    __builtin_amdgcn_global_load_lds(
        (const __attribute__((address_space(1))) void*)g,
        (__attribute__((address_space(3))) void*)l, 16, 0, 0);
}

// ---- prep: W [(K+1)][O] fp32 -> fp16 hi(/lo) planes [O][K] + bias[O] -------------
__global__ void prep_wT(const float* __restrict__ W, _Float16* __restrict__ WTh,
                        _Float16* __restrict__ WTl, float* __restrict__ bias,
                        int K, int O) {
    __shared__ float tile[32][33];
    int i0 = blockIdx.x * 32;   // K dim
    int o0 = blockIdx.y * 32;   // O dim
    int tx = threadIdx.x;       // 0..31
    int ty = threadIdx.y;       // 0..7
    for (int dy = 0; dy < 32; dy += 8)
        tile[ty + dy][tx] = W[(size_t)(i0 + ty + dy) * O + o0 + tx];
    if (blockIdx.x == 0 && ty == 0)
        bias[o0 + tx] = W[(size_t)K * O + o0 + tx];
    __syncthreads();
    for (int dy = 0; dy < 32; dy += 8) {
        float w = tile[tx][ty + dy];             // W[i0+tx][o0+ty+dy]
        size_t dst = (size_t)(o0 + ty + dy) * K + i0 + tx;
        _Float16 h = (_Float16)w;
        WTh[dst] = h;
        if (WTl) WTl[dst] = (_Float16)(w - (float)h);
    }
}

// ---- prep: x [64][512][256] fp32 -> xf [64][256][512] fp16 -----------------------
__global__ void prep_x1p(const float* __restrict__ x, _Float16* __restrict__ xf) {
    __shared__ float tile[32][33];
    int b = blockIdx.z;
    int i0 = blockIdx.x * 32;
    int t0 = blockIdx.y * 32;
    int tx = threadIdx.x;
    int ty = threadIdx.y;
    for (int dy = 0; dy < 32; dy += 8)
        tile[ty + dy][tx] = x[((size_t)b * 512 + i0 + ty + dy) * T_DIM + t0 + tx];
    __syncthreads();
    for (int dy = 0; dy < 32; dy += 8) {
        float w = tile[tx][ty + dy];
        size_t dst = ((size_t)b * T_DIM + t0 + ty + dy) * 512 + i0 + tx;
        xf[dst] = (_Float16)w;
    }
}

// ---- hidden-layer fused GEMM+LIF: 128(o) x 256(t), 8 waves (2M x 4N) --------------
// S[b][t][o] = LIF(sum_planes A_p·B + bias).  Per-wave inner loop = proven shape
// (acc[4][4] = 64 VGPR; kk asc, hi-then-lo per kk).  NP=1: LDS 48KB (A 16K + B 32K)
// -> 3 blocks/CU.  NP=2: LDS 64KB (Ah 16K + Al 16K + B 32K) -> 2 blocks/CU.
// Staging: NP=1: 6, NP=2: 8 gloads/thread/k-step.  B staged by O/128 blocks/batch.
// LIF epilogue: 4 chunks of 64 t dumped by the two wn==tc waves into fpool
// [64t][132o] (33.8KB), 128 threads scan with mem carried in registers.
// Accumulation order per output element identical to r15 -> bit-identical
// (absmax canary 2.585938).
template <int NP>
__global__ __launch_bounds__(512) void gemm_f16_lif8(
    const _Float16* __restrict__ Ah, const _Float16* __restrict__ Al,
    const _Float16* __restrict__ B,
    const float* __restrict__ bias, unsigned short* __restrict__ Sout,
    const float* __restrict__ beta_p, const float* __restrict__ thr_p,
    int O, int K) {
    __shared__ __align__(16) char pool[NP == 2 ? 65536 : 49152];
    char* Ash = pool;                      // 128 x 128B = 16KB
    char* Asl = pool + 16384;              // 16KB (NP==2 only)
    char* Bs  = pool + NP * 16384;         // 256 x 128B = 32KB

    const int nOx = O >> 7;                // o-groups of 128
    const int fid = blockIdx.x;
    const int xcd = fid & 7;
    const int k_in = fid >> 3;
    const int b = xcd * 8 + k_in / nOx;
    const int o0 = (k_in % nOx) * 128;

    const int tid = threadIdx.x;
    const int lane = tid & 63;
    const int wave = tid >> 6;             // 0..7
    const int wm = wave >> 2;              // 0..1 (o half)
    const int wn = wave & 3;               // 0..3 (t quarter)

    f32x4 acc[4][4] = {};

    const int srow = tid >> 3;             // 0..63
    const int skb  = (tid & 7) * 16;
    const int src_kb = skb ^ ((srow & 7) << 4);

    const _Float16* Bb = B + (size_t)b * T_DIM * K;

    for (int k0 = 0; k0 < K; k0 += 64) {
#pragma unroll
        for (int r = 0; r < 2; ++r) {
            int row = srow + r * 64;       // 0..127
            gload_lds16((const char*)(Ah + (size_t)(o0 + row) * K + k0) + src_kb,
                        Ash + row * 128 + skb);
            if (NP == 2)
                gload_lds16((const char*)(Al + (size_t)(o0 + row) * K + k0) + src_kb,
                            Asl + row * 128 + skb);
        }
#pragma unroll
        for (int r = 0; r < 4; ++r) {
            int row = srow + r * 64;       // 0..255
            gload_lds16((const char*)(Bb + (size_t)row * K + k0) + src_kb,
                        Bs + row * 128 + skb);
        }
        __syncthreads();
#pragma unroll
        for (int kk = 0; kk < 2; ++kk) {
            half8 afh[4], afl[4], bfr[4];
#pragma unroll
            for (int i = 0; i < 4; ++i) {
                int row = wm * 64 + i * 16 + (lane & 15);
                int kb = ((((lane >> 4) * 8) + kk * 32) * 2) ^ ((row & 7) << 4);
                afh[i] = *(const half8*)(Ash + row * 128 + kb);
                if (NP == 2) afl[i] = *(const half8*)(Asl + row * 128 + kb);
            }
#pragma unroll
            for (int j = 0; j < 4; ++j) {
                int row = wn * 64 + j * 16 + (lane & 15);
                int kb = ((((lane >> 4) * 8) + kk * 32) * 2) ^ ((row & 7) << 4);
                bfr[j] = *(const half8*)(Bs + row * 128 + kb);
            }
#pragma unroll
            for (int i = 0; i < 4; ++i)
#pragma unroll
                for (int j = 0; j < 4; ++j)
                    acc[i][j] = __builtin_amdgcn_mfma_f32_16x16x32_f16(
                        afh[i], bfr[j], acc[i][j], 0, 0, 0);
            if (NP == 2) {
#pragma unroll
                for (int i = 0; i < 4; ++i)
#pragma unroll
                    for (int j = 0; j < 4; ++j)
                        acc[i][j] = __builtin_amdgcn_mfma_f32_16x16x32_f16(
                            afl[i], bfr[j], acc[i][j], 0, 0, 0);
            }
        }
        __syncthreads();
    }

    // ---- fused LIF epilogue: 4 chunks of 64 t; fpool [64t][132o] = 33.8KB ---------
    float sb = 1.f / (1.f + expf(-beta_p[0]));
    float thrv = thr_p[0];
    float* fpool = (float*)pool;
    float mem = 0.f;
    for (int tc = 0; tc < 4; ++tc) {
        __syncthreads();
        if (wn == tc) {                    // two waves (wm = 0,1) dump this chunk
#pragma unroll
            for (int i = 0; i < 4; ++i) {
                int o = wm * 64 + i * 16 + ((lane >> 4) * 4);
                f32x4 bv = *(const f32x4*)(bias + o0 + o);
#pragma unroll
                for (int j = 0; j < 4; ++j) {
                    int tl = j * 16 + (lane & 15);
                    *(f32x4*)(fpool + tl * 132 + o) = acc[i][j] + bv;
                }
            }
        }
        __syncthreads();
        if (tid < 128) {
#pragma unroll 4
            for (int tt = 0; tt < 64; ++tt) {
                float mu = __fadd_rn(__fmul_rn(sb, mem), fpool[tt * 132 + tid]);
                float spike = (mu >= thrv) ? 1.f : 0.f;
                mem = mu - spike * thrv;
                Sout[((size_t)b * T_DIM + tc * 64 + tt) * O + o0 + tid] =
                    (mu >= thrv) ? (unsigned short)0x3C00 : (unsigned short)0;
            }
        }
    }
}

// ---- fp16 GEMM: two A planes (hi/lo) share one staged B (layer 3, proven) --------
template <int BN>
__global__ __launch_bounds__(256) void gemm_f16_2a1b(
    const _Float16* __restrict__ Ah, const _Float16* __restrict__ Al,
    const _Float16* __restrict__ B,
    const float* __restrict__ bias, float* __restrict__ Cout,
    int O, int K, int nOx, int nTy) {
    constexpr int NB = BN / 32;
    __shared__ char Ash[128 * 128];
    __shared__ char Asl[128 * 128];
    __shared__ char Bs[BN * 128];

    const int fid = blockIdx.x;
    const int bpb = nOx * nTy;
    const int xcd = fid & 7;
    const int k_in = fid >> 3;
    const int b = xcd * 8 + k_in / bpb;
    const int r_in = k_in % bpb;
    const int o0 = (r_in / nTy) * 128;
    const int t0 = (r_in % nTy) * BN;

    const int tid = threadIdx.x;
    const int lane = tid & 63;
    const int wave = tid >> 6;
    const int wm = wave >> 1, wn = wave & 1;

    f32x4 acc[4][NB] = {};

    const int srow = tid >> 3;
    const int skb  = (tid & 7) * 16;
    const int src_kb = skb ^ ((srow & 7) << 4);

    const _Float16* Bb = B + (size_t)b * T_DIM * K;

    for (int k0 = 0; k0 < K; k0 += 64) {
#pragma unroll
        for (int r = 0; r < 4; ++r) {
            int row = srow + r * 32;
            gload_lds16((const char*)(Ah + (size_t)(o0 + row) * K + k0) + src_kb,
                        Ash + row * 128 + skb);
            gload_lds16((const char*)(Al + (size_t)(o0 + row) * K + k0) + src_kb,
                        Asl + row * 128 + skb);
        }
#pragma unroll
        for (int r = 0; r < NB; ++r) {
            int row = srow + r * 32;
            gload_lds16((const char*)(Bb + (size_t)(t0 + row) * K + k0) + src_kb,
                        Bs + row * 128 + skb);
        }
        __syncthreads();
#pragma unroll
        for (int kk = 0; kk < 2; ++kk) {
            half8 afh[4], afl[4], bfr[NB];
#pragma unroll
            for (int i = 0; i < 4; ++i) {
                int row = wm * 64 + i * 16 + (lane & 15);
                int kb = ((((lane >> 4) * 8) + kk * 32) * 2) ^ ((row & 7) << 4);
                afh[i] = *(const half8*)(Ash + row * 128 + kb);
                afl[i] = *(const half8*)(Asl + row * 128 + kb);
            }
#pragma unroll
            for (int j = 0; j < NB; ++j) {
                int row = wn * (BN / 2) + j * 16 + (lane & 15);
                int kb = ((((lane >> 4) * 8) + kk * 32) * 2) ^ ((row & 7) << 4);
                bfr[j] = *(const half8*)(Bs + row * 128 + kb);
            }
#pragma unroll
            for (int i = 0; i < 4; ++i)
#pragma unroll
                for (int j = 0; j < NB; ++j)
                    acc[i][j] = __builtin_amdgcn_mfma_f32_16x16x32_f16(
                        afh[i], bfr[j], acc[i][j], 0, 0, 0);
#pragma unroll
            for (int i = 0; i < 4; ++i)
#pragma unroll
                for (int j = 0; j < NB; ++j)
                    acc[i][j] = __builtin_amdgcn_mfma_f32_16x16x32_f16(
                        afl[i], bfr[j], acc[i][j], 0, 0, 0);
        }
        __syncthreads();
    }
#pragma unroll
    for (int i = 0; i < 4; ++i) {
        int ob = o0 + wm * 64 + i * 16 + ((lane >> 4) * 4);
        f32x4 bv = *(const f32x4*)(bias + ob);
#pragma unroll
        for (int j = 0; j < NB; ++j) {
            int t = t0 + wn * (BN / 2) + j * 16 + (lane & 15);
            f32x4 v = acc[i][j] + bv;
            *(f32x4*)(Cout + ((size_t)b * T_DIM + t) * O + ob) = v;
        }
    }
}

// ---- LIF scan: final layer (LDS-transposed coalesced writes) ----------------------
__global__ __launch_bounds__(64) void lif_final_t(
    const float* __restrict__ pre, float* __restrict__ osp, float* __restrict__ omem,
    const float* __restrict__ beta_p, const float* __restrict__ thr_p) {
    __shared__ float spk[64][33];
    __shared__ float mm[64][33];
    int bid = blockIdx.x;
    int b = bid >> 2, og = bid & 3;
    int lane = threadIdx.x;
    float sb = 1.f / (1.f + expf(-beta_p[0]));
    float thr = thr_p[0];
    float mem = 0.f;
    const float* src = pre + (size_t)b * T_DIM * 256 + og * 64 + lane;
    int bo = b * 256 + og * 64;
    for (int c = 0; c < 8; ++c) {
        int t0 = c * 32;
        float xv[32];
#pragma unroll
        for (int tt = 0; tt < 32; ++tt)
            xv[tt] = src[(size_t)(t0 + tt) * 256];
#pragma unroll
        for (int tt = 0; tt < 32; ++tt) {
            mm[lane][tt] = mem;
            float mu = __fadd_rn(__fmul_rn(sb, mem), xv[tt]);
            float spike = (mu >= thr) ? 1.f : 0.f;
            spk[lane][tt] = spike;
            mem = mu - spike * thr;
        }
#pragma unroll
        for (int it = 0; it < 32; ++it) {
            int row = (lane >> 5) + 2 * it;
            int col = lane & 31;
            size_t dst = ((size_t)bo + row) * T_DIM + t0 + col;
            osp[dst] = spk[row][col];
            omem[dst] = mm[row][col];
        }
    }
}

extern "C" void kernel_launch(void* const* d_in, const int* in_sizes, int n_in,
                              void* d_out, int out_size, void* d_ws, size_t ws_size,
                              hipStream_t stream) {
    const float* x  = (const float*)d_in[0];
    const float* W0 = (const float*)d_in[1];
    const float* W1 = (const float*)d_in[2];
    const float* W2 = (const float*)d_in[3];
    const float* beta = (const float*)d_in[4];
    const float* thr  = (const float*)d_in[5];
    float* out = (float*)d_out;

    char* ws = (char*)d_ws;
    size_t off = 0;
    auto alloc = [&](size_t bytes) {
        size_t r = off;
        off = (off + bytes + 255) & ~(size_t)255;
        return r;
    };
    _Float16* w0h = (_Float16*)(ws + alloc(1024 * 512 * 2));
    _Float16* w0l = (_Float16*)(ws + alloc(1024 * 512 * 2));
    float* b0 = (float*)(ws + alloc(1024 * 4));
    _Float16* w1f = (_Float16*)(ws + alloc(1024 * 1024 * 2));
    float* b1 = (float*)(ws + alloc(1024 * 4));
    _Float16* w2h = (_Float16*)(ws + alloc(256 * 1024 * 2));
    _Float16* w2l = (_Float16*)(ws + alloc(256 * 1024 * 2));
    float* b2 = (float*)(ws + alloc(256 * 4));
    _Float16* xf = (_Float16*)(ws + alloc((size_t)NBATCH * T_DIM * 512 * 2));
    unsigned short* S1 = (unsigned short*)(ws + alloc((size_t)NBATCH * T_DIM * 1024 * 2));
    unsigned short* S2 = (unsigned short*)(ws + alloc((size_t)NBATCH * T_DIM * 1024 * 2));
    float* pre3 = (float*)(ws + alloc((size_t)NBATCH * T_DIM * 256 * 4));
    (void)ws_size; (void)in_sizes; (void)n_in; (void)out_size;

    // W preps: LDS-tiled transpose (coalesced both sides)
    prep_wT<<<dim3(16, 32), dim3(32, 8), 0, stream>>>(W0, w0h, w0l, b0, 512, 1024);
    prep_wT<<<dim3(32, 32), dim3(32, 8), 0, stream>>>(W1, w1f, nullptr, b1, 1024, 1024);
    prep_wT<<<dim3(32, 8),  dim3(32, 8), 0, stream>>>(W2, w2h, w2l, b2, 1024, 256);
    prep_x1p<<<dim3(16, 8, 64), dim3(32, 8), 0, stream>>>(x, xf);

    // Layer 1: fused fp16 GEMM+LIF, 2 planes, 128x256 tile, 8 waves; grid 512
    gemm_f16_lif8<2><<<dim3(512), 512, 0, stream>>>(w0h, w0l, xf, b0, S1, beta, thr,
                                                    1024, 512);
    // Layer 2: fused fp16 GEMM+LIF, single plane, 128x256 tile, 8 waves; grid 512
    gemm_f16_lif8<1><<<dim3(512), 512, 0, stream>>>(w1f, nullptr, (const _Float16*)S1,
                                                    b1, S2, beta, thr, 1024, 1024);
    // Layer 3: fp16 (Wh+Wl)·S2 (2-plane, guards output-mem precision), BN=64
    gemm_f16_2a1b<64><<<dim3(512), 256, 0, stream>>>(w2h, w2l, (const _Float16*)S2,
                                                     b2, pre3, 256, 1024, 2, 4);
    lif_final_t<<<dim3(256), 64, 0, stream>>>(pre3, out, out + (size_t)NBATCH * 256 * T_DIM,
                                              beta, thr);
}

// Round 17
// 134.060 us; speedup vs baseline: 1.8743x; 1.0650x over previous
//
#include <hip/hip_runtime.h>
#include <hip/hip_bf16.h>
#include <stdint.h>

typedef __attribute__((ext_vector_type(8))) _Float16 half8;
typedef __attribute__((ext_vector_type(4))) float f32x4;

#define T_DIM 256
#define NBATCH 64

__device__ __forceinline__ void gload_lds16(const void* g, void* l) {
    __builtin_amdgcn_global_load_lds(
        (const __attribute__((address_space(1))) void*)g,
        (__attribute__((address_space(3))) void*)l, 16, 0, 0);
}

// ---- merged prep: one dispatch does x-transpose + all three W transposes ----------
// grid sections (blocks of (32,8)):
//   [0, 8192)     x  [64][512][256] fp32 -> xf [64][256][512] fp16
//   [8192, 8704)  W0 [(512+1)][1024] -> w0h/w0l [1024][512] + b0
//   [8704, 9728)  W1 [(1024+1)][1024] -> w1f [1024][1024] + b1   (single plane)
//   [9728, 9984)  W2 [(1024+1)][256] -> w2h/w2l [256][1024] + b2
// Branches are uniform per block (blockIdx-based) -> __syncthreads safe.
__global__ void prep_all(const float* __restrict__ x, _Float16* __restrict__ xf,
                         const float* __restrict__ W0, _Float16* __restrict__ w0h,
                         _Float16* __restrict__ w0l, float* __restrict__ b0,
                         const float* __restrict__ W1, _Float16* __restrict__ w1f,
                         float* __restrict__ b1,
                         const float* __restrict__ W2, _Float16* __restrict__ w2h,
                         _Float16* __restrict__ w2l, float* __restrict__ b2) {
    __shared__ float tile[32][33];
    const int id = blockIdx.x;
    const int tx = threadIdx.x;   // 0..31
    const int ty = threadIdx.y;   // 0..7

    if (id < 8192) {
        // ---- x transpose + fp16 convert ----
        int b = id >> 7;
        int rem = id & 127;
        int i0 = (rem & 15) * 32;   // input dim 512
        int t0 = (rem >> 4) * 32;   // time 256
        for (int dy = 0; dy < 32; dy += 8)
            tile[ty + dy][tx] = x[((size_t)b * 512 + i0 + ty + dy) * T_DIM + t0 + tx];
        __syncthreads();
        for (int dy = 0; dy < 32; dy += 8) {
            float w = tile[tx][ty + dy];
            size_t dst = ((size_t)b * T_DIM + t0 + ty + dy) * 512 + i0 + tx;
            xf[dst] = (_Float16)w;
        }
        return;
    }

    // ---- W transpose + hi/lo split ----
    const float* W;
    _Float16 *Wh, *Wl;
    float* bias;
    int K, O, i0, o0;
    if (id < 8704) {
        int id2 = id - 8192;                 // 16 i-tiles x 32 o-tiles
        W = W0; Wh = w0h; Wl = w0l; bias = b0; K = 512; O = 1024;
        i0 = (id2 & 15) * 32; o0 = (id2 >> 4) * 32;
    } else if (id < 9728) {
        int id3 = id - 8704;                 // 32 x 32
        W = W1; Wh = w1f; Wl = nullptr; bias = b1; K = 1024; O = 1024;
        i0 = (id3 & 31) * 32; o0 = (id3 >> 5) * 32;
    } else {
        int id4 = id - 9728;                 // 32 i x 8 o
        W = W2; Wh = w2h; Wl = w2l; bias = b2; K = 1024; O = 256;
        i0 = (id4 & 31) * 32; o0 = (id4 >> 5) * 32;
    }
    for (int dy = 0; dy < 32; dy += 8)
        tile[ty + dy][tx] = W[(size_t)(i0 + ty + dy) * O + o0 + tx];
    if (i0 == 0 && ty == 0)
        bias[o0 + tx] = W[(size_t)K * O + o0 + tx];
    __syncthreads();
    for (int dy = 0; dy < 32; dy += 8) {
        float w = tile[tx][ty + dy];         // W[i0+tx][o0+ty+dy]
        size_t dst = (size_t)(o0 + ty + dy) * K + i0 + tx;
        _Float16 h = (_Float16)w;
        Wh[dst] = h;
        if (Wl) Wl[dst] = (_Float16)(w - (float)h);
    }
}

// ---- hidden-layer fused GEMM+LIF: 128(o) x 256(t), 8 waves (2M x 4N) --------------
// S[b][t][o] = LIF(sum_planes A_p·B + bias).  Per-wave inner loop = proven shape
// (acc[4][4] = 64 VGPR; kk asc, hi-then-lo per kk).  NP=1: LDS 48KB -> grid-capped
// 2 blocks/CU.  NP=2: LDS 64KB -> 2 blocks/CU.  LIF epilogue: 4 chunks of 64 t
// dumped by the two wn==tc waves into fpool [64t][132o], 128 threads scan with mem
// carried in registers.  Accumulation order identical to r16 -> bit-identical
// (absmax canary 2.585938).
template <int NP>
__global__ __launch_bounds__(512) void gemm_f16_lif8(
    const _Float16* __restrict__ Ah, const _Float16* __restrict__ Al,
    const _Float16* __restrict__ B,
    const float* __restrict__ bias, unsigned short* __restrict__ Sout,
    const float* __restrict__ beta_p, const float* __restrict__ thr_p,
    int O, int K) {
    __shared__ __align__(16) char pool[NP == 2 ? 65536 : 49152];
    char* Ash = pool;                      // 128 x 128B = 16KB
    char* Asl = pool + 16384;              // 16KB (NP==2 only)
    char* Bs  = pool + NP * 16384;         // 256 x 128B = 32KB

    const int nOx = O >> 7;                // o-groups of 128
    const int fid = blockIdx.x;
    const int xcd = fid & 7;
    const int k_in = fid >> 3;
    const int b = xcd * 8 + k_in / nOx;
    const int o0 = (k_in % nOx) * 128;

    const int tid = threadIdx.x;
    const int lane = tid & 63;
    const int wave = tid >> 6;             // 0..7
    const int wm = wave >> 2;              // 0..1 (o half)
    const int wn = wave & 3;               // 0..3 (t quarter)

    f32x4 acc[4][4] = {};

    const int srow = tid >> 3;             // 0..63
    const int skb  = (tid & 7) * 16;
    const int src_kb = skb ^ ((srow & 7) << 4);

    const _Float16* Bb = B + (size_t)b * T_DIM * K;

    for (int k0 = 0; k0 < K; k0 += 64) {
#pragma unroll
        for (int r = 0; r < 2; ++r) {
            int row = srow + r * 64;       // 0..127
            gload_lds16((const char*)(Ah + (size_t)(o0 + row) * K + k0) + src_kb,
                        Ash + row * 128 + skb);
            if (NP == 2)
                gload_lds16((const char*)(Al + (size_t)(o0 + row) * K + k0) + src_kb,
                            Asl + row * 128 + skb);
        }
#pragma unroll
        for (int r = 0; r < 4; ++r) {
            int row = srow + r * 64;       // 0..255
            gload_lds16((const char*)(Bb + (size_t)row * K + k0) + src_kb,
                        Bs + row * 128 + skb);
        }
        __syncthreads();
#pragma unroll
        for (int kk = 0; kk < 2; ++kk) {
            half8 afh[4], afl[4], bfr[4];
#pragma unroll
            for (int i = 0; i < 4; ++i) {
                int row = wm * 64 + i * 16 + (lane & 15);
                int kb = ((((lane >> 4) * 8) + kk * 32) * 2) ^ ((row & 7) << 4);
                afh[i] = *(const half8*)(Ash + row * 128 + kb);
                if (NP == 2) afl[i] = *(const half8*)(Asl + row * 128 + kb);
            }
#pragma unroll
            for (int j = 0; j < 4; ++j) {
                int row = wn * 64 + j * 16 + (lane & 15);
                int kb = ((((lane >> 4) * 8) + kk * 32) * 2) ^ ((row & 7) << 4);
                bfr[j] = *(const half8*)(Bs + row * 128 + kb);
            }
#pragma unroll
            for (int i = 0; i < 4; ++i)
#pragma unroll
                for (int j = 0; j < 4; ++j)
                    acc[i][j] = __builtin_amdgcn_mfma_f32_16x16x32_f16(
                        afh[i], bfr[j], acc[i][j], 0, 0, 0);
            if (NP == 2) {
#pragma unroll
                for (int i = 0; i < 4; ++i)
#pragma unroll
                    for (int j = 0; j < 4; ++j)
                        acc[i][j] = __builtin_amdgcn_mfma_f32_16x16x32_f16(
                            afl[i], bfr[j], acc[i][j], 0, 0, 0);
            }
        }
        __syncthreads();
    }

    // ---- fused LIF epilogue: 4 chunks of 64 t; fpool [64t][132o] = 33.8KB ---------
    float sb = 1.f / (1.f + expf(-beta_p[0]));
    float thrv = thr_p[0];
    float* fpool = (float*)pool;
    float mem = 0.f;
    for (int tc = 0; tc < 4; ++tc) {
        __syncthreads();
        if (wn == tc) {                    // two waves (wm = 0,1) dump this chunk
#pragma unroll
            for (int i = 0; i < 4; ++i) {
                int o = wm * 64 + i * 16 + ((lane >> 4) * 4);
                f32x4 bv = *(const f32x4*)(bias + o0 + o);
#pragma unroll
                for (int j = 0; j < 4; ++j) {
                    int tl = j * 16 + (lane & 15);
                    *(f32x4*)(fpool + tl * 132 + o) = acc[i][j] + bv;
                }
            }
        }
        __syncthreads();
        if (tid < 128) {
#pragma unroll 4
            for (int tt = 0; tt < 64; ++tt) {
                float mu = __fadd_rn(__fmul_rn(sb, mem), fpool[tt * 132 + tid]);
                float spike = (mu >= thrv) ? 1.f : 0.f;
                mem = mu - spike * thrv;
                Sout[((size_t)b * T_DIM + tc * 64 + tt) * O + o0 + tid] =
                    (mu >= thrv) ? (unsigned short)0x3C00 : (unsigned short)0;
            }
        }
    }
}

// ---- fp16 GEMM: two A planes (hi/lo) share one staged B (layer 3, proven) --------
template <int BN>
__global__ __launch_bounds__(256) void gemm_f16_2a1b(
    const _Float16* __restrict__ Ah, const _Float16* __restrict__ Al,
    const _Float16* __restrict__ B,
    const float* __restrict__ bias, float* __restrict__ Cout,
    int O, int K, int nOx, int nTy) {
    constexpr int NB = BN / 32;
    __shared__ char Ash[128 * 128];
    __shared__ char Asl[128 * 128];
    __shared__ char Bs[BN * 128];

    const int fid = blockIdx.x;
    const int bpb = nOx * nTy;
    const int xcd = fid & 7;
    const int k_in = fid >> 3;
    const int b = xcd * 8 + k_in / bpb;
    const int r_in = k_in % bpb;
    const int o0 = (r_in / nTy) * 128;
    const int t0 = (r_in % nTy) * BN;

    const int tid = threadIdx.x;
    const int lane = tid & 63;
    const int wave = tid >> 6;
    const int wm = wave >> 1, wn = wave & 1;

    f32x4 acc[4][NB] = {};

    const int srow = tid >> 3;
    const int skb  = (tid & 7) * 16;
    const int src_kb = skb ^ ((srow & 7) << 4);

    const _Float16* Bb = B + (size_t)b * T_DIM * K;

    for (int k0 = 0; k0 < K; k0 += 64) {
#pragma unroll
        for (int r = 0; r < 4; ++r) {
            int row = srow + r * 32;
            gload_lds16((const char*)(Ah + (size_t)(o0 + row) * K + k0) + src_kb,
                        Ash + row * 128 + skb);
            gload_lds16((const char*)(Al + (size_t)(o0 + row) * K + k0) + src_kb,
                        Asl + row * 128 + skb);
        }
#pragma unroll
        for (int r = 0; r < NB; ++r) {
            int row = srow + r * 32;
            gload_lds16((const char*)(Bb + (size_t)(t0 + row) * K + k0) + src_kb,
                        Bs + row * 128 + skb);
        }
        __syncthreads();
#pragma unroll
        for (int kk = 0; kk < 2; ++kk) {
            half8 afh[4], afl[4], bfr[NB];
#pragma unroll
            for (int i = 0; i < 4; ++i) {
                int row = wm * 64 + i * 16 + (lane & 15);
                int kb = ((((lane >> 4) * 8) + kk * 32) * 2) ^ ((row & 7) << 4);
                afh[i] = *(const half8*)(Ash + row * 128 + kb);
                afl[i] = *(const half8*)(Asl + row * 128 + kb);
            }
#pragma unroll
            for (int j = 0; j < NB; ++j) {
                int row = wn * (BN / 2) + j * 16 + (lane & 15);
                int kb = ((((lane >> 4) * 8) + kk * 32) * 2) ^ ((row & 7) << 4);
                bfr[j] = *(const half8*)(Bs + row * 128 + kb);
            }
#pragma unroll
            for (int i = 0; i < 4; ++i)
#pragma unroll
                for (int j = 0; j < NB; ++j)
                    acc[i][j] = __builtin_amdgcn_mfma_f32_16x16x32_f16(
                        afh[i], bfr[j], acc[i][j], 0, 0, 0);
#pragma unroll
            for (int i = 0; i < 4; ++i)
#pragma unroll
                for (int j = 0; j < NB; ++j)
                    acc[i][j] = __builtin_amdgcn_mfma_f32_16x16x32_f16(
                        afl[i], bfr[j], acc[i][j], 0, 0, 0);
        }
        __syncthreads();
    }
#pragma unroll
    for (int i = 0; i < 4; ++i) {
        int ob = o0 + wm * 64 + i * 16 + ((lane >> 4) * 4);
        f32x4 bv = *(const f32x4*)(bias + ob);
#pragma unroll
        for (int j = 0; j < NB; ++j) {
            int t = t0 + wn * (BN / 2) + j * 16 + (lane & 15);
            f32x4 v = acc[i][j] + bv;
            *(f32x4*)(Cout + ((size_t)b * T_DIM + t) * O + ob) = v;
        }
    }
}

// ---- LIF scan: final layer (LDS-transposed coalesced writes) ----------------------
__global__ __launch_bounds__(64) void lif_final_t(
    const float* __restrict__ pre, float* __restrict__ osp, float* __restrict__ omem,
    const float* __restrict__ beta_p, const float* __restrict__ thr_p) {
    __shared__ float spk[64][33];
    __shared__ float mm[64][33];
    int bid = blockIdx.x;
    int b = bid >> 2, og = bid & 3;
    int lane = threadIdx.x;
    float sb = 1.f / (1.f + expf(-beta_p[0]));
    float thr = thr_p[0];
    float mem = 0.f;
    const float* src = pre + (size_t)b * T_DIM * 256 + og * 64 + lane;
    int bo = b * 256 + og * 64;
    for (int c = 0; c < 8; ++c) {
        int t0 = c * 32;
        float xv[32];
#pragma unroll
        for (int tt = 0; tt < 32; ++tt)
            xv[tt] = src[(size_t)(t0 + tt) * 256];
#pragma unroll
        for (int tt = 0; tt < 32; ++tt) {
            mm[lane][tt] = mem;
            float mu = __fadd_rn(__fmul_rn(sb, mem), xv[tt]);
            float spike = (mu >= thr) ? 1.f : 0.f;
            spk[lane][tt] = spike;
            mem = mu - spike * thr;
        }
#pragma unroll
        for (int it = 0; it < 32; ++it) {
            int row = (lane >> 5) + 2 * it;
            int col = lane & 31;
            size_t dst = ((size_t)bo + row) * T_DIM + t0 + col;
            osp[dst] = spk[row][col];
            omem[dst] = mm[row][col];
        }
    }
}

extern "C" void kernel_launch(void* const* d_in, const int* in_sizes, int n_in,
                              void* d_out, int out_size, void* d_ws, size_t ws_size,
                              hipStream_t stream) {
    const float* x  = (const float*)d_in[0];
    const float* W0 = (const float*)d_in[1];
    const float* W1 = (const float*)d_in[2];
    const float* W2 = (const float*)d_in[3];
    const float* beta = (const float*)d_in[4];
    const float* thr  = (const float*)d_in[5];
    float* out = (float*)d_out;

    char* ws = (char*)d_ws;
    size_t off = 0;
    auto alloc = [&](size_t bytes) {
        size_t r = off;
        off = (off + bytes + 255) & ~(size_t)255;
        return r;
    };
    _Float16* w0h = (_Float16*)(ws + alloc(1024 * 512 * 2));
    _Float16* w0l = (_Float16*)(ws + alloc(1024 * 512 * 2));
    float* b0 = (float*)(ws + alloc(1024 * 4));
    _Float16* w1f = (_Float16*)(ws + alloc(1024 * 1024 * 2));
    float* b1 = (float*)(ws + alloc(1024 * 4));
    _Float16* w2h = (_Float16*)(ws + alloc(256 * 1024 * 2));
    _Float16* w2l = (_Float16*)(ws + alloc(256 * 1024 * 2));
    float* b2 = (float*)(ws + alloc(256 * 4));
    _Float16* xf = (_Float16*)(ws + alloc((size_t)NBATCH * T_DIM * 512 * 2));
    unsigned short* S1 = (unsigned short*)(ws + alloc((size_t)NBATCH * T_DIM * 1024 * 2));
    unsigned short* S2 = (unsigned short*)(ws + alloc((size_t)NBATCH * T_DIM * 1024 * 2));
    float* pre3 = (float*)(ws + alloc((size_t)NBATCH * T_DIM * 256 * 4));
    (void)ws_size; (void)in_sizes; (void)n_in; (void)out_size;

    // merged prep: x transpose + all W transposes in ONE dispatch
    prep_all<<<dim3(9984), dim3(32, 8), 0, stream>>>(x, xf,
                                                     W0, w0h, w0l, b0,
                                                     W1, w1f, b1,
                                                     W2, w2h, w2l, b2);

    // Layer 1: fused fp16 GEMM+LIF, 2 planes, 128x256 tile, 8 waves; grid 512
    gemm_f16_lif8<2><<<dim3(512), 512, 0, stream>>>(w0h, w0l, xf, b0, S1, beta, thr,
                                                    1024, 512);
    // Layer 2: fused fp16 GEMM+LIF, single plane, 128x256 tile, 8 waves; grid 512
    gemm_f16_lif8<1><<<dim3(512), 512, 0, stream>>>(w1f, nullptr, (const _Float16*)S1,
                                                    b1, S2, beta, thr, 1024, 1024);
    // Layer 3: fp16 (Wh+Wl)·S2 (2-plane, guards output-mem precision), BN=64
    gemm_f16_2a1b<64><<<dim3(512), 256, 0, stream>>>(w2h, w2l, (const _Float16*)S2,
                                                     b2, pre3, 256, 1024, 2, 4);
    lif_final_t<<<dim3(256), 64, 0, stream>>>(pre3, out, out + (size_t)NBATCH * 256 * T_DIM,
                                              beta, thr);
}

// Round 18
// 128.792 us; speedup vs baseline: 1.9509x; 1.0409x over previous
//
#include <hip/hip_runtime.h>
#include <hip/hip_bf16.h>
#include <stdint.h>

typedef __attribute__((ext_vector_type(8))) _Float16 half8;
typedef __attribute__((ext_vector_type(4))) float f32x4;

#define T_DIM 256
#define NBATCH 64

__device__ __forceinline__ void gload_lds16(const void* g, void* l) {
    __builtin_amdgcn_global_load_lds(
        (const __attribute__((address_space(1))) void*)g,
        (__attribute__((address_space(3))) void*)l, 16, 0, 0);
}

// ---- merged prep: one dispatch does x-transpose + all three W transposes ----------
// grid sections (blocks of (32,8)):
//   [0, 8192)     x  [64][512][256] fp32 -> xf [64][256][512] fp16
//   [8192, 8704)  W0 [(512+1)][1024] -> w0h/w0l [1024][512] + b0
//   [8704, 9728)  W1 [(1024+1)][1024] -> w1f [1024][1024] + b1   (single plane)
//   [9728, 9984)  W2 [(1024+1)][256] -> w2f [256][1024] + b2     (single plane)
__global__ void prep_all(const float* __restrict__ x, _Float16* __restrict__ xf,
                         const float* __restrict__ W0, _Float16* __restrict__ w0h,
                         _Float16* __restrict__ w0l, float* __restrict__ b0,
                         const float* __restrict__ W1, _Float16* __restrict__ w1f,
                         float* __restrict__ b1,
                         const float* __restrict__ W2, _Float16* __restrict__ w2f,
                         float* __restrict__ b2) {
    __shared__ float tile[32][33];
    const int id = blockIdx.x;
    const int tx = threadIdx.x;   // 0..31
    const int ty = threadIdx.y;   // 0..7

    if (id < 8192) {
        int b = id >> 7;
        int rem = id & 127;
        int i0 = (rem & 15) * 32;   // input dim 512
        int t0 = (rem >> 4) * 32;   // time 256
        for (int dy = 0; dy < 32; dy += 8)
            tile[ty + dy][tx] = x[((size_t)b * 512 + i0 + ty + dy) * T_DIM + t0 + tx];
        __syncthreads();
        for (int dy = 0; dy < 32; dy += 8) {
            float w = tile[tx][ty + dy];
            size_t dst = ((size_t)b * T_DIM + t0 + ty + dy) * 512 + i0 + tx;
            xf[dst] = (_Float16)w;
        }
        return;
    }

    const float* W;
    _Float16 *Wh, *Wl;
    float* bias;
    int K, O, i0, o0;
    if (id < 8704) {
        int id2 = id - 8192;                 // 16 i-tiles x 32 o-tiles
        W = W0; Wh = w0h; Wl = w0l; bias = b0; K = 512; O = 1024;
        i0 = (id2 & 15) * 32; o0 = (id2 >> 4) * 32;
    } else if (id < 9728) {
        int id3 = id - 8704;                 // 32 x 32
        W = W1; Wh = w1f; Wl = nullptr; bias = b1; K = 1024; O = 1024;
        i0 = (id3 & 31) * 32; o0 = (id3 >> 5) * 32;
    } else {
        int id4 = id - 9728;                 // 32 i x 8 o
        W = W2; Wh = w2f; Wl = nullptr; bias = b2; K = 1024; O = 256;
        i0 = (id4 & 31) * 32; o0 = (id4 >> 5) * 32;
    }
    for (int dy = 0; dy < 32; dy += 8)
        tile[ty + dy][tx] = W[(size_t)(i0 + ty + dy) * O + o0 + tx];
    if (i0 == 0 && ty == 0)
        bias[o0 + tx] = W[(size_t)K * O + o0 + tx];
    __syncthreads();
    for (int dy = 0; dy < 32; dy += 8) {
        float w = tile[tx][ty + dy];         // W[i0+tx][o0+ty+dy]
        size_t dst = (size_t)(o0 + ty + dy) * K + i0 + tx;
        _Float16 h = (_Float16)w;
        Wh[dst] = h;
        if (Wl) Wl[dst] = (_Float16)(w - (float)h);
    }
}

// ---- hidden-layer fused GEMM+LIF: 128(o) x 256(t), 8 waves (2M x 4N) --------------
// (unchanged from r17 — absmax canary 2.585938 depends on this staying identical)
template <int NP>
__global__ __launch_bounds__(512) void gemm_f16_lif8(
    const _Float16* __restrict__ Ah, const _Float16* __restrict__ Al,
    const _Float16* __restrict__ B,
    const float* __restrict__ bias, unsigned short* __restrict__ Sout,
    const float* __restrict__ beta_p, const float* __restrict__ thr_p,
    int O, int K) {
    __shared__ __align__(16) char pool[NP == 2 ? 65536 : 49152];
    char* Ash = pool;                      // 128 x 128B = 16KB
    char* Asl = pool + 16384;              // 16KB (NP==2 only)
    char* Bs  = pool + NP * 16384;         // 256 x 128B = 32KB

    const int nOx = O >> 7;                // o-groups of 128
    const int fid = blockIdx.x;
    const int xcd = fid & 7;
    const int k_in = fid >> 3;
    const int b = xcd * 8 + k_in / nOx;
    const int o0 = (k_in % nOx) * 128;

    const int tid = threadIdx.x;
    const int lane = tid & 63;
    const int wave = tid >> 6;             // 0..7
    const int wm = wave >> 2;              // 0..1 (o half)
    const int wn = wave & 3;               // 0..3 (t quarter)

    f32x4 acc[4][4] = {};

    const int srow = tid >> 3;             // 0..63
    const int skb  = (tid & 7) * 16;
    const int src_kb = skb ^ ((srow & 7) << 4);

    const _Float16* Bb = B + (size_t)b * T_DIM * K;

    for (int k0 = 0; k0 < K; k0 += 64) {
#pragma unroll
        for (int r = 0; r < 2; ++r) {
            int row = srow + r * 64;       // 0..127
            gload_lds16((const char*)(Ah + (size_t)(o0 + row) * K + k0) + src_kb,
                        Ash + row * 128 + skb);
            if (NP == 2)
                gload_lds16((const char*)(Al + (size_t)(o0 + row) * K + k0) + src_kb,
                            Asl + row * 128 + skb);
        }
#pragma unroll
        for (int r = 0; r < 4; ++r) {
            int row = srow + r * 64;       // 0..255
            gload_lds16((const char*)(Bb + (size_t)row * K + k0) + src_kb,
                        Bs + row * 128 + skb);
        }
        __syncthreads();
#pragma unroll
        for (int kk = 0; kk < 2; ++kk) {
            half8 afh[4], afl[4], bfr[4];
#pragma unroll
            for (int i = 0; i < 4; ++i) {
                int row = wm * 64 + i * 16 + (lane & 15);
                int kb = ((((lane >> 4) * 8) + kk * 32) * 2) ^ ((row & 7) << 4);
                afh[i] = *(const half8*)(Ash + row * 128 + kb);
                if (NP == 2) afl[i] = *(const half8*)(Asl + row * 128 + kb);
            }
#pragma unroll
            for (int j = 0; j < 4; ++j) {
                int row = wn * 64 + j * 16 + (lane & 15);
                int kb = ((((lane >> 4) * 8) + kk * 32) * 2) ^ ((row & 7) << 4);
                bfr[j] = *(const half8*)(Bs + row * 128 + kb);
            }
#pragma unroll
            for (int i = 0; i < 4; ++i)
#pragma unroll
                for (int j = 0; j < 4; ++j)
                    acc[i][j] = __builtin_amdgcn_mfma_f32_16x16x32_f16(
                        afh[i], bfr[j], acc[i][j], 0, 0, 0);
            if (NP == 2) {
#pragma unroll
                for (int i = 0; i < 4; ++i)
#pragma unroll
                    for (int j = 0; j < 4; ++j)
                        acc[i][j] = __builtin_amdgcn_mfma_f32_16x16x32_f16(
                            afl[i], bfr[j], acc[i][j], 0, 0, 0);
            }
        }
        __syncthreads();
    }

    // ---- fused LIF epilogue: 4 chunks of 64 t; fpool [64t][132o] = 33.8KB ---------
    float sb = 1.f / (1.f + expf(-beta_p[0]));
    float thrv = thr_p[0];
    float* fpool = (float*)pool;
    float mem = 0.f;
    for (int tc = 0; tc < 4; ++tc) {
        __syncthreads();
        if (wn == tc) {                    // two waves (wm = 0,1) dump this chunk
#pragma unroll
            for (int i = 0; i < 4; ++i) {
                int o = wm * 64 + i * 16 + ((lane >> 4) * 4);
                f32x4 bv = *(const f32x4*)(bias + o0 + o);
#pragma unroll
                for (int j = 0; j < 4; ++j) {
                    int tl = j * 16 + (lane & 15);
                    *(f32x4*)(fpool + tl * 132 + o) = acc[i][j] + bv;
                }
            }
        }
        __syncthreads();
        if (tid < 128) {
#pragma unroll 4
            for (int tt = 0; tt < 64; ++tt) {
                float mu = __fadd_rn(__fmul_rn(sb, mem), fpool[tt * 132 + tid]);
                float spike = (mu >= thrv) ? 1.f : 0.f;
                mem = mu - spike * thrv;
                Sout[((size_t)b * T_DIM + tc * 64 + tt) * O + o0 + tid] =
                    (mu >= thrv) ? (unsigned short)0x3C00 : (unsigned short)0;
            }
        }
    }
}

// ---- layer-3 fp16 GEMM: SINGLE plane (was hi/lo), 128 x BN tile -------------------
template <int BN>
__global__ __launch_bounds__(256) void gemm_f16_1p(
    const _Float16* __restrict__ A, const _Float16* __restrict__ B,
    const float* __restrict__ bias, float* __restrict__ Cout,
    int O, int K, int nOx, int nTy) {
    constexpr int NB = BN / 32;
    __shared__ char Ash[128 * 128];
    __shared__ char Bs[BN * 128];

    const int fid = blockIdx.x;
    const int bpb = nOx * nTy;
    const int xcd = fid & 7;
    const int k_in = fid >> 3;
    const int b = xcd * 8 + k_in / bpb;
    const int r_in = k_in % bpb;
    const int o0 = (r_in / nTy) * 128;
    const int t0 = (r_in % nTy) * BN;

    const int tid = threadIdx.x;
    const int lane = tid & 63;
    const int wave = tid >> 6;
    const int wm = wave >> 1, wn = wave & 1;

    f32x4 acc[4][NB] = {};

    const int srow = tid >> 3;
    const int skb  = (tid & 7) * 16;
    const int src_kb = skb ^ ((srow & 7) << 4);

    const _Float16* Bb = B + (size_t)b * T_DIM * K;

    for (int k0 = 0; k0 < K; k0 += 64) {
#pragma unroll
        for (int r = 0; r < 4; ++r) {
            int row = srow + r * 32;
            gload_lds16((const char*)(A + (size_t)(o0 + row) * K + k0) + src_kb,
                        Ash + row * 128 + skb);
        }
#pragma unroll
        for (int r = 0; r < NB; ++r) {
            int row = srow + r * 32;
            gload_lds16((const char*)(Bb + (size_t)(t0 + row) * K + k0) + src_kb,
                        Bs + row * 128 + skb);
        }
        __syncthreads();
#pragma unroll
        for (int kk = 0; kk < 2; ++kk) {
            half8 af[4], bfr[NB];
#pragma unroll
            for (int i = 0; i < 4; ++i) {
                int row = wm * 64 + i * 16 + (lane & 15);
                int kb = ((((lane >> 4) * 8) + kk * 32) * 2) ^ ((row & 7) << 4);
                af[i] = *(const half8*)(Ash + row * 128 + kb);
            }
#pragma unroll
            for (int j = 0; j < NB; ++j) {
                int row = wn * (BN / 2) + j * 16 + (lane & 15);
                int kb = ((((lane >> 4) * 8) + kk * 32) * 2) ^ ((row & 7) << 4);
                bfr[j] = *(const half8*)(Bs + row * 128 + kb);
            }
#pragma unroll
            for (int i = 0; i < 4; ++i)
#pragma unroll
                for (int j = 0; j < NB; ++j)
                    acc[i][j] = __builtin_amdgcn_mfma_f32_16x16x32_f16(
                        af[i], bfr[j], acc[i][j], 0, 0, 0);
        }
        __syncthreads();
    }
#pragma unroll
    for (int i = 0; i < 4; ++i) {
        int ob = o0 + wm * 64 + i * 16 + ((lane >> 4) * 4);
        f32x4 bv = *(const f32x4*)(bias + ob);
#pragma unroll
        for (int j = 0; j < NB; ++j) {
            int t = t0 + wn * (BN / 2) + j * 16 + (lane & 15);
            f32x4 v = acc[i][j] + bv;
            *(f32x4*)(Cout + ((size_t)b * T_DIM + t) * O + ob) = v;
        }
    }
}

// ---- LIF scan: final layer (LDS-transposed coalesced writes) ----------------------
__global__ __launch_bounds__(64) void lif_final_t(
    const float* __restrict__ pre, float* __restrict__ osp, float* __restrict__ omem,
    const float* __restrict__ beta_p, const float* __restrict__ thr_p) {
    __shared__ float spk[64][33];
    __shared__ float mm[64][33];
    int bid = blockIdx.x;
    int b = bid >> 2, og = bid & 3;
    int lane = threadIdx.x;
    float sb = 1.f / (1.f + expf(-beta_p[0]));
    float thr = thr_p[0];
    float mem = 0.f;
    const float* src = pre + (size_t)b * T_DIM * 256 + og * 64 + lane;
    int bo = b * 256 + og * 64;
    for (int c = 0; c < 8; ++c) {
        int t0 = c * 32;
        float xv[32];
#pragma unroll
        for (int tt = 0; tt < 32; ++tt)
            xv[tt] = src[(size_t)(t0 + tt) * 256];
#pragma unroll
        for (int tt = 0; tt < 32; ++tt) {
            mm[lane][tt] = mem;
            float mu = __fadd_rn(__fmul_rn(sb, mem), xv[tt]);
            float spike = (mu >= thr) ? 1.f : 0.f;
            spk[lane][tt] = spike;
            mem = mu - spike * thr;
        }
#pragma unroll
        for (int it = 0; it < 32; ++it) {
            int row = (lane >> 5) + 2 * it;
            int col = lane & 31;
            size_t dst = ((size_t)bo + row) * T_DIM + t0 + col;
            osp[dst] = spk[row][col];
            omem[dst] = mm[row][col];
        }
    }
}

extern "C" void kernel_launch(void* const* d_in, const int* in_sizes, int n_in,
                              void* d_out, int out_size, void* d_ws, size_t ws_size,
                              hipStream_t stream) {
    const float* x  = (const float*)d_in[0];
    const float* W0 = (const float*)d_in[1];
    const float* W1 = (const float*)d_in[2];
    const float* W2 = (const float*)d_in[3];
    const float* beta = (const float*)d_in[4];
    const float* thr  = (const float*)d_in[5];
    float* out = (float*)d_out;

    char* ws = (char*)d_ws;
    size_t off = 0;
    auto alloc = [&](size_t bytes) {
        size_t r = off;
        off = (off + bytes + 255) & ~(size_t)255;
        return r;
    };
    _Float16* w0h = (_Float16*)(ws + alloc(1024 * 512 * 2));
    _Float16* w0l = (_Float16*)(ws + alloc(1024 * 512 * 2));
    float* b0 = (float*)(ws + alloc(1024 * 4));
    _Float16* w1f = (_Float16*)(ws + alloc(1024 * 1024 * 2));
    float* b1 = (float*)(ws + alloc(1024 * 4));
    _Float16* w2f = (_Float16*)(ws + alloc(256 * 1024 * 2));
    float* b2 = (float*)(ws + alloc(256 * 4));
    _Float16* xf = (_Float16*)(ws + alloc((size_t)NBATCH * T_DIM * 512 * 2));
    unsigned short* S1 = (unsigned short*)(ws + alloc((size_t)NBATCH * T_DIM * 1024 * 2));
    unsigned short* S2 = (unsigned short*)(ws + alloc((size_t)NBATCH * T_DIM * 1024 * 2));
    float* pre3 = (float*)(ws + alloc((size_t)NBATCH * T_DIM * 256 * 4));
    (void)ws_size; (void)in_sizes; (void)n_in; (void)out_size;

    // merged prep: x transpose + all W transposes in ONE dispatch
    prep_all<<<dim3(9984), dim3(32, 8), 0, stream>>>(x, xf,
                                                     W0, w0h, w0l, b0,
                                                     W1, w1f, b1,
                                                     W2, w2f, b2);

    // Layer 1: fused fp16 GEMM+LIF, 2 planes, 128x256 tile, 8 waves; grid 512
    gemm_f16_lif8<2><<<dim3(512), 512, 0, stream>>>(w0h, w0l, xf, b0, S1, beta, thr,
                                                    1024, 512);
    // Layer 2: fused fp16 GEMM+LIF, single plane, 128x256 tile, 8 waves; grid 512
    gemm_f16_lif8<1><<<dim3(512), 512, 0, stream>>>(w1f, nullptr, (const _Float16*)S1,
                                                    b1, S2, beta, thr, 1024, 1024);
    // Layer 3: fp16 single-plane W2·S2, BN=64 -> grid 512
    gemm_f16_1p<64><<<dim3(512), 256, 0, stream>>>(w2f, (const _Float16*)S2,
                                                   b2, pre3, 256, 1024, 2, 4);
    lif_final_t<<<dim3(256), 64, 0, stream>>>(pre3, out, out + (size_t)NBATCH * 256 * T_DIM,
                                              beta, thr);
}